// Round 1
// baseline (11615.928 us; speedup 1.0000x reference)
//
#include <hip/hip_runtime.h>
#include <math.h>

#define D 512
#define H 8
#define DH 64
#define NLAYERS 8
#define DFF 8
#define NC 10
#define KITERS 10
#define SEQ 1026
#define BATCH 16
#define MR (BATCH*SEQ)            // 16416 rows
#define NBUF ((size_t)MR * D)     // floats per big buffer

__device__ __forceinline__ float pe_val(int s, int d) {
    float e = (float)(d & ~1);
    float dv = expf(e * (-9.210340371976184f / 512.0f));   // ln(10000)/512
    float ph = (float)s * dv;
    return (d & 1) ? cosf(ph) : sinf(ph);
}

// ---------------- embed ----------------
// grid: (258, 16). bx=0 -> s=0 (mu), bx=1 -> s=1 (sigma), bx>=2 -> 4 frames f0=(bx-2)*4.
__launch_bounds__(256)
__global__ void embed_kernel(const float* __restrict__ x, const int* __restrict__ y,
    const float* __restrict__ muQ, const float* __restrict__ sigQ,
    const float* __restrict__ mu_w, const float* __restrict__ mu_b,
    const float* __restrict__ sig_w, const float* __restrict__ sig_b,
    const float* __restrict__ skel_w, const float* __restrict__ skel_b,
    float* __restrict__ z)
{
    __shared__ float xin[3072];
    const int bx = blockIdx.x, b = blockIdx.y, tid = threadIdx.x;
    if (bx < 2) {
        const float* Q  = (bx == 0) ? muQ  : sigQ;
        const float* W  = (bx == 0) ? mu_w : sig_w;
        const float* bb = (bx == 0) ? mu_b : sig_b;
        for (int i = tid; i < 3072; i += 256) {
            int a = y[b*6 + (i >> 9)];
            xin[i] = Q[a*D + (i & 511)];
        }
        __syncthreads();
        const int d0 = tid, d1 = tid + 256;
        float acc0 = bb[d0], acc1 = bb[d1];
        const float4* x4 = (const float4*)xin;
        for (int i4 = 0; i4 < 768; ++i4) {
            float4 xv = x4[i4];
            int r = i4 * 4;
            acc0 += xv.x*W[(size_t)(r+0)*D+d0] + xv.y*W[(size_t)(r+1)*D+d0]
                  + xv.z*W[(size_t)(r+2)*D+d0] + xv.w*W[(size_t)(r+3)*D+d0];
            acc1 += xv.x*W[(size_t)(r+0)*D+d1] + xv.y*W[(size_t)(r+1)*D+d1]
                  + xv.z*W[(size_t)(r+2)*D+d1] + xv.w*W[(size_t)(r+3)*D+d1];
        }
        size_t base = ((size_t)b*SEQ + bx) * D;
        z[base + d0] = acc0 + pe_val(bx, d0);
        z[base + d1] = acc1 + pe_val(bx, d1);
    } else {
        const int f0 = (bx - 2) * 4;
        for (int idx = tid; idx < 600; idx += 256) {
            int i = idx >> 2, ff = idx & 3;
            xin[idx] = x[((size_t)(b*150 + i))*1024 + f0 + ff];
        }
        __syncthreads();
        const float4* x4 = (const float4*)xin;
        for (int dd = 0; dd < 2; ++dd) {
            const int d = tid + dd*256;
            float a0, a1, a2, a3;
            a0 = a1 = a2 = a3 = skel_b[d];
            for (int i = 0; i < 150; ++i) {
                float4 xv = x4[i];
                float w = skel_w[(size_t)i*D + d];
                a0 += xv.x*w; a1 += xv.y*w; a2 += xv.z*w; a3 += xv.w*w;
            }
            float a[4] = {a0, a1, a2, a3};
            #pragma unroll
            for (int ff = 0; ff < 4; ++ff) {
                int s = f0 + ff + 2;
                z[((size_t)b*SEQ + s)*D + d] = a[ff] + pe_val(s, d);
            }
        }
    }
}

// ---------------- GEMM (M x 512) @ (512 x 512) ----------------
// EPI 0: out scattered to q/k/v layout (b*H+h, s, dh), += bias
// EPI 1: out[m*512+n] = acc + bias[n] + resid[m*512+n]
__device__ __forceinline__ float4 ld_guard(const float* A, int m, int kcol, int M) {
    if (m < M) return *(const float4*)&A[(size_t)m*D + kcol];
    return make_float4(0.f, 0.f, 0.f, 0.f);
}

template<int EPI>
__launch_bounds__(256, 2)
__global__ void gemm512(const float* __restrict__ A, const float* __restrict__ W,
                        const float* __restrict__ bias, const float* __restrict__ resid,
                        float* __restrict__ out, int M)
{
    __shared__ float As[16*132];
    __shared__ float Bs[16*132];
    const int tid = threadIdx.x;
    const int tx = tid & 15, ty = tid >> 4;
    const int m0 = blockIdx.y * 128, n0 = blockIdx.x * 128;
    const int ar = tid >> 2, ac = (tid & 3) * 4;
    const int bkr = tid >> 5, bqc = (tid & 31) * 4;

    float acc[8][8];
    #pragma unroll
    for (int i = 0; i < 8; ++i)
        #pragma unroll
        for (int j = 0; j < 8; ++j) acc[i][j] = 0.f;

    for (int kt = 0; kt < 32; ++kt) {
        const int kb = kt * 16;
        float4 a0 = ld_guard(A, m0 + ar,      kb + ac, M);
        float4 a1 = ld_guard(A, m0 + ar + 64, kb + ac, M);
        float4 b0 = *(const float4*)&W[(size_t)(kb + bkr    )*D + n0 + bqc];
        float4 b1 = *(const float4*)&W[(size_t)(kb + bkr + 8)*D + n0 + bqc];
        if (kt) __syncthreads();
        As[(ac+0)*132 + ar] = a0.x; As[(ac+1)*132 + ar] = a0.y;
        As[(ac+2)*132 + ar] = a0.z; As[(ac+3)*132 + ar] = a0.w;
        As[(ac+0)*132 + ar + 64] = a1.x; As[(ac+1)*132 + ar + 64] = a1.y;
        As[(ac+2)*132 + ar + 64] = a1.z; As[(ac+3)*132 + ar + 64] = a1.w;
        *(float4*)&Bs[bkr*132 + bqc] = b0;
        *(float4*)&Bs[(bkr+8)*132 + bqc] = b1;
        __syncthreads();
        #pragma unroll
        for (int k = 0; k < 16; ++k) {
            float4 alo = *(const float4*)&As[k*132 + ty*4];
            float4 ahi = *(const float4*)&As[k*132 + 64 + ty*4];
            float4 blo = *(const float4*)&Bs[k*132 + tx*4];
            float4 bhi = *(const float4*)&Bs[k*132 + 64 + tx*4];
            float av[8] = {alo.x, alo.y, alo.z, alo.w, ahi.x, ahi.y, ahi.z, ahi.w};
            float bv[8] = {blo.x, blo.y, blo.z, blo.w, bhi.x, bhi.y, bhi.z, bhi.w};
            #pragma unroll
            for (int i = 0; i < 8; ++i)
                #pragma unroll
                for (int j = 0; j < 8; ++j) acc[i][j] += av[i] * bv[j];
        }
    }

    float4 blo = *(const float4*)&bias[n0 + tx*4];
    float4 bhi = *(const float4*)&bias[n0 + 64 + tx*4];
    #pragma unroll
    for (int i = 0; i < 8; ++i) {
        int m = m0 + ((i >> 2) << 6) + ty*4 + (i & 3);
        if (m >= M) continue;
        float o0 = acc[i][0] + blo.x, o1 = acc[i][1] + blo.y;
        float o2 = acc[i][2] + blo.z, o3 = acc[i][3] + blo.w;
        float o4 = acc[i][4] + bhi.x, o5 = acc[i][5] + bhi.y;
        float o6 = acc[i][6] + bhi.z, o7 = acc[i][7] + bhi.w;
        if (EPI == 0) {
            int bb = m / SEQ;
            int ss = m - bb * SEQ;
            int nlo = n0 + tx*4, nhi = nlo + 64;
            float* plo = out + ((size_t)(bb*H + (nlo >> 6)))*((size_t)SEQ*DH) + (size_t)ss*DH + (nlo & 63);
            float* phi = out + ((size_t)(bb*H + (nhi >> 6)))*((size_t)SEQ*DH) + (size_t)ss*DH + (nhi & 63);
            *(float4*)plo = make_float4(o0, o1, o2, o3);
            *(float4*)phi = make_float4(o4, o5, o6, o7);
        } else {
            size_t off = (size_t)m*D + n0 + tx*4;
            float4 r0 = *(const float4*)&resid[off];
            float4 r1 = *(const float4*)&resid[off + 64];
            *(float4*)&out[off]      = make_float4(o0+r0.x, o1+r0.y, o2+r0.z, o3+r0.w);
            *(float4*)&out[off + 64] = make_float4(o4+r1.x, o5+r1.y, o6+r1.z, o7+r1.w);
        }
    }
}

// ---------------- clustered attention, one block per (b,h) ----------------
#define ARGMIN_ONE(ACC, SPOS) { \
    int best = 0; float bd = cnorm[0] - 2.f*ACC[0]; \
    _Pragma("unroll") \
    for (int c = 1; c < NC; ++c) { \
        float dd = cnorm[c] - 2.f*ACC[c]; \
        if (dd < bd) { bd = dd; best = c; } \
    } \
    assign[SPOS] = (unsigned char)best; \
    if (docnt) atomicAdd(&cnt4[tid>>6][best], 1); \
}

__launch_bounds__(256)
__global__ void attn_kernel(const float* __restrict__ q, const float* __restrict__ kk,
                            const float* __restrict__ v, float* __restrict__ o)
{
    __shared__ float cent[NC][DH];      // centroids; reused as attn_out at the end
    __shared__ float cnorm[NC];
    __shared__ float part[4][NC][DH];
    __shared__ int   cnt4[4][NC];
    __shared__ unsigned char assign[SEQ];
    __shared__ float logits[NC][SEQ];
    __shared__ float red[8];

    const int tid = threadIdx.x;
    const int bh = blockIdx.x;
    const int b = bh >> 3, h = bh & 7;
    const float* qh = q  + (size_t)bh * SEQ * DH;
    const float* kh = kk + (size_t)bh * SEQ * DH;
    const float* vh = v  + (size_t)bh * SEQ * DH;
    float* oh = o + (size_t)b * SEQ * D + h * DH;

    for (int i = tid; i < NC*DH; i += 256) ((float*)cent)[i] = qh[i];
    __syncthreads();

    for (int iter = 0; iter <= KITERS; ++iter) {
        if (tid < NC) {
            float sn = 0.f;
            for (int d = 0; d < DH; ++d) { float c = cent[tid][d]; sn += c*c; }
            cnorm[tid] = sn;
        }
        if (tid >= 64 && tid < 64 + 4*NC) ((int*)cnt4)[tid - 64] = 0;
        __syncthreads();

        // ---- assignment pass (4 strided positions per thread + 2-pos tail) ----
        {
            const bool docnt = (iter < KITERS);
            float a0[NC], a1[NC], a2[NC], a3[NC];
            #pragma unroll
            for (int c = 0; c < NC; ++c) { a0[c]=0.f; a1[c]=0.f; a2[c]=0.f; a3[c]=0.f; }
            const float4* q4 = (const float4*)qh;
            #pragma unroll 4
            for (int kq = 0; kq < 16; ++kq) {
                float4 v0 = q4[(size_t)(tid      )*16 + kq];
                float4 v1 = q4[(size_t)(tid + 256)*16 + kq];
                float4 v2 = q4[(size_t)(tid + 512)*16 + kq];
                float4 v3 = q4[(size_t)(tid + 768)*16 + kq];
                #pragma unroll
                for (int c = 0; c < NC; ++c) {
                    float4 cv = *(const float4*)&cent[c][kq*4];
                    a0[c] += v0.x*cv.x + v0.y*cv.y + v0.z*cv.z + v0.w*cv.w;
                    a1[c] += v1.x*cv.x + v1.y*cv.y + v1.z*cv.z + v1.w*cv.w;
                    a2[c] += v2.x*cv.x + v2.y*cv.y + v2.z*cv.z + v2.w*cv.w;
                    a3[c] += v3.x*cv.x + v3.y*cv.y + v3.z*cv.z + v3.w*cv.w;
                }
            }
            ARGMIN_ONE(a0, tid)
            ARGMIN_ONE(a1, tid + 256)
            ARGMIN_ONE(a2, tid + 512)
            ARGMIN_ONE(a3, tid + 768)
            if (tid < 2) {
                const int s = 1024 + tid;
                float at[NC];
                #pragma unroll
                for (int c = 0; c < NC; ++c) at[c] = 0.f;
                for (int kq = 0; kq < 16; ++kq) {
                    float4 qv = q4[(size_t)s*16 + kq];
                    #pragma unroll
                    for (int c = 0; c < NC; ++c) {
                        float4 cv = *(const float4*)&cent[c][kq*4];
                        at[c] += qv.x*cv.x + qv.y*cv.y + qv.z*cv.z + qv.w*cv.w;
                    }
                }
                ARGMIN_ONE(at, s)
            }
        }
        __syncthreads();
        if (iter == KITERS) break;

        // ---- centroid update (register accumulators, predicated adds) ----
        {
            const int g = tid >> 6, d = tid & 63;
            const int s0g = g * 257;
            const int s1g = (g == 3) ? SEQ : (s0g + 257);
            float accq[NC];
            #pragma unroll
            for (int c = 0; c < NC; ++c) accq[c] = 0.f;
            for (int s = s0g; s < s1g; ++s) {
                float qv = qh[(size_t)s*DH + d];
                int c = assign[s];
                #pragma unroll
                for (int cc = 0; cc < NC; ++cc) accq[cc] += (cc == c) ? qv : 0.f;
            }
            #pragma unroll
            for (int c = 0; c < NC; ++c) part[g][c][d] = accq[c];
        }
        __syncthreads();
        for (int i = tid; i < NC*DH; i += 256) {
            int c = i >> 6;
            float s = ((float*)part)[i] + ((float*)part)[640 + i]
                    + ((float*)part)[1280 + i] + ((float*)part)[1920 + i];
            float cn = (float)(cnt4[0][c] + cnt4[1][c] + cnt4[2][c] + cnt4[3][c]);
            ((float*)cent)[i] = s / fmaxf(cn, 1.f);
        }
        __syncthreads();
    }

    // ---- logits = temp * cent @ k^T ----
    {
        float a0[NC], a1[NC], a2[NC], a3[NC];
        #pragma unroll
        for (int c = 0; c < NC; ++c) { a0[c]=0.f; a1[c]=0.f; a2[c]=0.f; a3[c]=0.f; }
        const float4* k4 = (const float4*)kh;
        #pragma unroll 4
        for (int kq = 0; kq < 16; ++kq) {
            float4 v0 = k4[(size_t)(tid      )*16 + kq];
            float4 v1 = k4[(size_t)(tid + 256)*16 + kq];
            float4 v2 = k4[(size_t)(tid + 512)*16 + kq];
            float4 v3 = k4[(size_t)(tid + 768)*16 + kq];
            #pragma unroll
            for (int c = 0; c < NC; ++c) {
                float4 cv = *(const float4*)&cent[c][kq*4];
                a0[c] += v0.x*cv.x + v0.y*cv.y + v0.z*cv.z + v0.w*cv.w;
                a1[c] += v1.x*cv.x + v1.y*cv.y + v1.z*cv.z + v1.w*cv.w;
                a2[c] += v2.x*cv.x + v2.y*cv.y + v2.z*cv.z + v2.w*cv.w;
                a3[c] += v3.x*cv.x + v3.y*cv.y + v3.z*cv.z + v3.w*cv.w;
            }
        }
        #pragma unroll
        for (int c = 0; c < NC; ++c) {
            logits[c][tid      ] = 0.125f * a0[c];
            logits[c][tid + 256] = 0.125f * a1[c];
            logits[c][tid + 512] = 0.125f * a2[c];
            logits[c][tid + 768] = 0.125f * a3[c];
        }
        if (tid < 2) {
            const int s = 1024 + tid;
            float at[NC];
            #pragma unroll
            for (int c = 0; c < NC; ++c) at[c] = 0.f;
            for (int kq = 0; kq < 16; ++kq) {
                float4 qv = k4[(size_t)s*16 + kq];
                #pragma unroll
                for (int c = 0; c < NC; ++c) {
                    float4 cv = *(const float4*)&cent[c][kq*4];
                    at[c] += qv.x*cv.x + qv.y*cv.y + qv.z*cv.z + qv.w*cv.w;
                }
            }
            #pragma unroll
            for (int c = 0; c < NC; ++c) logits[c][s] = 0.125f * at[c];
        }
    }
    __syncthreads();

    // ---- softmax over each cluster row ----
    const int lane = tid & 63, wid = tid >> 6;
    for (int c = 0; c < NC; ++c) {
        float m = -1e30f;
        for (int s = tid; s < SEQ; s += 256) m = fmaxf(m, logits[c][s]);
        #pragma unroll
        for (int off = 32; off; off >>= 1) m = fmaxf(m, __shfl_xor(m, off, 64));
        if (lane == 0) red[wid] = m;
        __syncthreads();
        m = fmaxf(fmaxf(red[0], red[1]), fmaxf(red[2], red[3]));
        __syncthreads();
        float ps = 0.f;
        for (int s = tid; s < SEQ; s += 256) {
            float e = expf(logits[c][s] - m);
            logits[c][s] = e;
            ps += e;
        }
        #pragma unroll
        for (int off = 32; off; off >>= 1) ps += __shfl_xor(ps, off, 64);
        if (lane == 0) red[4 + wid] = ps;
        __syncthreads();
        float inv = 1.f / (red[4] + red[5] + red[6] + red[7]);
        for (int s = tid; s < SEQ; s += 256) logits[c][s] *= inv;
        __syncthreads();
    }

    // ---- A @ v ----
    {
        const int g = tid >> 6, d = tid & 63;
        const int s0g = g * 257;
        const int s1g = (g == 3) ? SEQ : (s0g + 257);
        float accv[NC];
        #pragma unroll
        for (int c = 0; c < NC; ++c) accv[c] = 0.f;
        for (int s = s0g; s < s1g; ++s) {
            float vv = vh[(size_t)s*DH + d];
            #pragma unroll
            for (int c = 0; c < NC; ++c) accv[c] += logits[c][s] * vv;
        }
        #pragma unroll
        for (int c = 0; c < NC; ++c) part[g][c][d] = accv[c];
    }
    __syncthreads();
    for (int i = tid; i < NC*DH; i += 256) {
        ((float*)cent)[i] = ((float*)part)[i] + ((float*)part)[640 + i]
                          + ((float*)part)[1280 + i] + ((float*)part)[1920 + i];
    }
    __syncthreads();

    // ---- gather to output (b, s, h*64+d) ----
    {
        const int g = tid >> 6, d = tid & 63;
        for (int s = g; s < SEQ; s += 4) {
            oh[(size_t)s*D + d] = cent[assign[s]][d];
        }
    }
}

// ---------------- fused LN1 + FFN + residual + LN2, one block per row ----------------
__launch_bounds__(256)
__global__ void ffn_ln_kernel(const float* __restrict__ in, float* __restrict__ z,
    const float* __restrict__ g1, const float* __restrict__ c1,
    const float* __restrict__ W1, const float* __restrict__ b1,
    const float* __restrict__ W2, const float* __restrict__ b2,
    const float* __restrict__ g2, const float* __restrict__ c2)
{
    __shared__ float red[8];
    __shared__ float redh[4][DFF];
    const int row = blockIdx.x, tid = threadIdx.x;
    const int lane = tid & 63, wid = tid >> 6;
    const float* r = in + (size_t)row * D;
    float x0 = r[tid], x1 = r[tid + 256];
    float s = x0 + x1, ss = x0*x0 + x1*x1;
    #pragma unroll
    for (int off = 32; off; off >>= 1) {
        s  += __shfl_xor(s,  off, 64);
        ss += __shfl_xor(ss, off, 64);
    }
    if (lane == 0) { red[wid] = s; red[4 + wid] = ss; }
    __syncthreads();
    float tot  = red[0] + red[1] + red[2] + red[3];
    float tot2 = red[4] + red[5] + red[6] + red[7];
    float mean = tot * (1.f/512.f);
    float var  = tot2 * (1.f/512.f) - mean*mean;
    float rstd = rsqrtf(var + 1e-5f);
    float za = (x0 - mean)*rstd*g1[tid]       + c1[tid];
    float zb = (x1 - mean)*rstd*g1[tid + 256] + c1[tid + 256];

    float p[DFF];
    #pragma unroll
    for (int j = 0; j < DFF; ++j)
        p[j] = za * W1[(size_t)tid*DFF + j] + zb * W1[(size_t)(tid+256)*DFF + j];
    #pragma unroll
    for (int off = 32; off; off >>= 1)
        #pragma unroll
        for (int j = 0; j < DFF; ++j) p[j] += __shfl_xor(p[j], off, 64);
    if (lane == 0) {
        #pragma unroll
        for (int j = 0; j < DFF; ++j) redh[wid][j] = p[j];
    }
    __syncthreads();
    float hv[DFF];
    #pragma unroll
    for (int j = 0; j < DFF; ++j)
        hv[j] = fmaxf(redh[0][j] + redh[1][j] + redh[2][j] + redh[3][j] + b1[j], 0.f);
    float y0 = b2[tid], y1 = b2[tid + 256];
    #pragma unroll
    for (int j = 0; j < DFF; ++j) {
        y0 += hv[j] * W2[(size_t)j*D + tid];
        y1 += hv[j] * W2[(size_t)j*D + tid + 256];
    }
    float t0 = za + y0, t1 = zb + y1;
    float s2 = t0 + t1, ss2 = t0*t0 + t1*t1;
    #pragma unroll
    for (int off = 32; off; off >>= 1) {
        s2  += __shfl_xor(s2,  off, 64);
        ss2 += __shfl_xor(ss2, off, 64);
    }
    if (lane == 0) { red[wid] = s2; red[4 + wid] = ss2; }
    __syncthreads();
    float tt  = red[0] + red[1] + red[2] + red[3];
    float tt2 = red[4] + red[5] + red[6] + red[7];
    float m2 = tt * (1.f/512.f);
    float v2 = tt2 * (1.f/512.f) - m2*m2;
    float rstd2 = rsqrtf(v2 + 1e-5f);
    float* zo = z + (size_t)row * D;
    zo[tid]       = (t0 - m2)*rstd2*g2[tid]       + c2[tid];
    zo[tid + 256] = (t1 - m2)*rstd2*g2[tid + 256] + c2[tid + 256];
}

// ---------------- extract mu / logvar ----------------
__launch_bounds__(256)
__global__ void extract_kernel(const float* __restrict__ z, float* __restrict__ out) {
    int i = blockIdx.x * 256 + threadIdx.x;
    if (i >= 2*BATCH*D) return;
    int half = i >> 13;          // 0: mu (s=0), 1: logvar (s=1)
    int j = i & 8191;
    int b = j >> 9, d = j & 511;
    out[i] = z[((size_t)b*SEQ + half)*D + d];
}

extern "C" void kernel_launch(void* const* d_in, const int* in_sizes, int n_in,
                              void* d_out, int out_size, void* d_ws, size_t ws_size,
                              hipStream_t stream)
{
    const float* x      = (const float*)d_in[0];
    const int*   y      = (const int*)  d_in[1];
    // d_in[2] = mask, unused
    const float* muQ    = (const float*)d_in[3];
    const float* sigQ   = (const float*)d_in[4];
    const float* mu_w   = (const float*)d_in[5];
    const float* mu_b   = (const float*)d_in[6];
    const float* sig_w  = (const float*)d_in[7];
    const float* sig_b  = (const float*)d_in[8];
    const float* skel_w = (const float*)d_in[9];
    const float* skel_b = (const float*)d_in[10];
    const float* Wq     = (const float*)d_in[11];
    const float* bq     = (const float*)d_in[12];
    const float* Wk     = (const float*)d_in[13];
    const float* bk     = (const float*)d_in[14];
    const float* Wv     = (const float*)d_in[15];
    const float* bv     = (const float*)d_in[16];
    const float* Wo     = (const float*)d_in[17];
    const float* bo     = (const float*)d_in[18];
    const float* g1     = (const float*)d_in[19];
    const float* c1     = (const float*)d_in[20];
    const float* g2     = (const float*)d_in[21];
    const float* c2     = (const float*)d_in[22];
    const float* W1     = (const float*)d_in[23];
    const float* b1     = (const float*)d_in[24];
    const float* W2     = (const float*)d_in[25];
    const float* b2     = (const float*)d_in[26];

    float* z  = (float*)d_ws;
    float* ob = z  + NBUF;   // attention output (B,S,D); also o-proj input
    float* qb = ob + NBUF;   // q (B*H,S,DH); reused as o-proj output
    float* kb = qb + NBUF;
    float* vb = kb + NBUF;

    embed_kernel<<<dim3(258, BATCH), 256, 0, stream>>>(
        x, y, muQ, sigQ, mu_w, mu_b, sig_w, sig_b, skel_w, skel_b, z);

    dim3 ggrid(4, 129);
    for (int l = 0; l < NLAYERS; ++l) {
        gemm512<0><<<ggrid, 256, 0, stream>>>(z, Wq + (size_t)l*D*D, bq + l*D, nullptr, qb, MR);
        gemm512<0><<<ggrid, 256, 0, stream>>>(z, Wk + (size_t)l*D*D, bk + l*D, nullptr, kb, MR);
        gemm512<0><<<ggrid, 256, 0, stream>>>(z, Wv + (size_t)l*D*D, bv + l*D, nullptr, vb, MR);
        attn_kernel<<<BATCH*H, 256, 0, stream>>>(qb, kb, vb, ob);
        gemm512<1><<<ggrid, 256, 0, stream>>>(ob, Wo + (size_t)l*D*D, bo + l*D, z, qb, MR);
        ffn_ln_kernel<<<MR, 256, 0, stream>>>(qb, z,
            g1 + (size_t)l*D, c1 + (size_t)l*D,
            W1 + (size_t)l*D*DFF, b1 + (size_t)l*DFF,
            W2 + (size_t)l*DFF*D, b2 + (size_t)l*D,
            g2 + (size_t)l*D, c2 + (size_t)l*D);
    }
    extract_kernel<<<64, 256, 0, stream>>>(z, (float*)d_out);

    (void)in_sizes; (void)n_in; (void)out_size; (void)ws_size;
}

// Round 2
// 9983.971 us; speedup vs baseline: 1.1635x; 1.1635x over previous
//
#include <hip/hip_runtime.h>
#include <math.h>

#define D 512
#define H 8
#define DH 64
#define NLAYERS 8
#define DFF 8
#define NC 10
#define KITERS 10
#define SEQ 1026
#define SEQP 1032
#define BATCH 16
#define MR (BATCH*SEQ)            // 16416 rows
#define NBUF ((size_t)MR * D)     // floats per big buffer

__device__ __forceinline__ float pe_val(int s, int d) {
    float e = (float)(d & ~1);
    float dv = expf(e * (-9.210340371976184f / 512.0f));   // ln(10000)/512
    float ph = (float)s * dv;
    return (d & 1) ? cosf(ph) : sinf(ph);
}

// ---------------- embed ----------------
__launch_bounds__(256)
__global__ void embed_kernel(const float* __restrict__ x, const int* __restrict__ y,
    const float* __restrict__ muQ, const float* __restrict__ sigQ,
    const float* __restrict__ mu_w, const float* __restrict__ mu_b,
    const float* __restrict__ sig_w, const float* __restrict__ sig_b,
    const float* __restrict__ skel_w, const float* __restrict__ skel_b,
    float* __restrict__ z)
{
    __shared__ float xin[3072];
    const int bx = blockIdx.x, b = blockIdx.y, tid = threadIdx.x;
    if (bx < 2) {
        const float* Q  = (bx == 0) ? muQ  : sigQ;
        const float* W  = (bx == 0) ? mu_w : sig_w;
        const float* bb = (bx == 0) ? mu_b : sig_b;
        for (int i = tid; i < 3072; i += 256) {
            int a = y[b*6 + (i >> 9)];
            xin[i] = Q[a*D + (i & 511)];
        }
        __syncthreads();
        const int d0 = tid, d1 = tid + 256;
        float acc0 = bb[d0], acc1 = bb[d1];
        const float4* x4 = (const float4*)xin;
        for (int i4 = 0; i4 < 768; ++i4) {
            float4 xv = x4[i4];
            int r = i4 * 4;
            acc0 += xv.x*W[(size_t)(r+0)*D+d0] + xv.y*W[(size_t)(r+1)*D+d0]
                  + xv.z*W[(size_t)(r+2)*D+d0] + xv.w*W[(size_t)(r+3)*D+d0];
            acc1 += xv.x*W[(size_t)(r+0)*D+d1] + xv.y*W[(size_t)(r+1)*D+d1]
                  + xv.z*W[(size_t)(r+2)*D+d1] + xv.w*W[(size_t)(r+3)*D+d1];
        }
        size_t base = ((size_t)b*SEQ + bx) * D;
        z[base + d0] = acc0 + pe_val(bx, d0);
        z[base + d1] = acc1 + pe_val(bx, d1);
    } else {
        const int f0 = (bx - 2) * 4;
        for (int idx = tid; idx < 600; idx += 256) {
            int i = idx >> 2, ff = idx & 3;
            xin[idx] = x[((size_t)(b*150 + i))*1024 + f0 + ff];
        }
        __syncthreads();
        const float4* x4 = (const float4*)xin;
        for (int dd = 0; dd < 2; ++dd) {
            const int d = tid + dd*256;
            float a0, a1, a2, a3;
            a0 = a1 = a2 = a3 = skel_b[d];
            for (int i = 0; i < 150; ++i) {
                float4 xv = x4[i];
                float w = skel_w[(size_t)i*D + d];
                a0 += xv.x*w; a1 += xv.y*w; a2 += xv.z*w; a3 += xv.w*w;
            }
            float a[4] = {a0, a1, a2, a3};
            #pragma unroll
            for (int ff = 0; ff < 4; ++ff) {
                int s = f0 + ff + 2;
                z[((size_t)b*SEQ + s)*D + d] = a[ff] + pe_val(s, d);
            }
        }
    }
}

// ---------------- GEMM (M x 512) @ (512 x 512) ----------------
__device__ __forceinline__ float4 ld_guard(const float* A, int m, int kcol, int M) {
    if (m < M) return *(const float4*)&A[(size_t)m*D + kcol];
    return make_float4(0.f, 0.f, 0.f, 0.f);
}

template<int EPI>
__launch_bounds__(256, 2)
__global__ void gemm512(const float* __restrict__ A, const float* __restrict__ W,
                        const float* __restrict__ bias, const float* __restrict__ resid,
                        float* __restrict__ out, int M)
{
    __shared__ float As[16*132];
    __shared__ float Bs[16*132];
    const int tid = threadIdx.x;
    const int tx = tid & 15, ty = tid >> 4;
    const int m0 = blockIdx.y * 128, n0 = blockIdx.x * 128;
    const int ar = tid >> 2, ac = (tid & 3) * 4;
    const int bkr = tid >> 5, bqc = (tid & 31) * 4;

    float acc[8][8];
    #pragma unroll
    for (int i = 0; i < 8; ++i)
        #pragma unroll
        for (int j = 0; j < 8; ++j) acc[i][j] = 0.f;

    for (int kt = 0; kt < 32; ++kt) {
        const int kb = kt * 16;
        float4 a0 = ld_guard(A, m0 + ar,      kb + ac, M);
        float4 a1 = ld_guard(A, m0 + ar + 64, kb + ac, M);
        float4 b0 = *(const float4*)&W[(size_t)(kb + bkr    )*D + n0 + bqc];
        float4 b1 = *(const float4*)&W[(size_t)(kb + bkr + 8)*D + n0 + bqc];
        if (kt) __syncthreads();
        As[(ac+0)*132 + ar] = a0.x; As[(ac+1)*132 + ar] = a0.y;
        As[(ac+2)*132 + ar] = a0.z; As[(ac+3)*132 + ar] = a0.w;
        As[(ac+0)*132 + ar + 64] = a1.x; As[(ac+1)*132 + ar + 64] = a1.y;
        As[(ac+2)*132 + ar + 64] = a1.z; As[(ac+3)*132 + ar + 64] = a1.w;
        *(float4*)&Bs[bkr*132 + bqc] = b0;
        *(float4*)&Bs[(bkr+8)*132 + bqc] = b1;
        __syncthreads();
        #pragma unroll
        for (int k = 0; k < 16; ++k) {
            float4 alo = *(const float4*)&As[k*132 + ty*4];
            float4 ahi = *(const float4*)&As[k*132 + 64 + ty*4];
            float4 blo = *(const float4*)&Bs[k*132 + tx*4];
            float4 bhi = *(const float4*)&Bs[k*132 + 64 + tx*4];
            float av[8] = {alo.x, alo.y, alo.z, alo.w, ahi.x, ahi.y, ahi.z, ahi.w};
            float bv[8] = {blo.x, blo.y, blo.z, blo.w, bhi.x, bhi.y, bhi.z, bhi.w};
            #pragma unroll
            for (int i = 0; i < 8; ++i)
                #pragma unroll
                for (int j = 0; j < 8; ++j) acc[i][j] += av[i] * bv[j];
        }
    }

    float4 blo = *(const float4*)&bias[n0 + tx*4];
    float4 bhi = *(const float4*)&bias[n0 + 64 + tx*4];
    #pragma unroll
    for (int i = 0; i < 8; ++i) {
        int m = m0 + ((i >> 2) << 6) + ty*4 + (i & 3);
        if (m >= M) continue;
        float o0 = acc[i][0] + blo.x, o1 = acc[i][1] + blo.y;
        float o2 = acc[i][2] + blo.z, o3 = acc[i][3] + blo.w;
        float o4 = acc[i][4] + bhi.x, o5 = acc[i][5] + bhi.y;
        float o6 = acc[i][6] + bhi.z, o7 = acc[i][7] + bhi.w;
        if (EPI == 0) {
            int bb = m / SEQ;
            int ss = m - bb * SEQ;
            int nlo = n0 + tx*4, nhi = nlo + 64;
            float* plo = out + ((size_t)(bb*H + (nlo >> 6)))*((size_t)SEQ*DH) + (size_t)ss*DH + (nlo & 63);
            float* phi = out + ((size_t)(bb*H + (nhi >> 6)))*((size_t)SEQ*DH) + (size_t)ss*DH + (nhi & 63);
            *(float4*)plo = make_float4(o0, o1, o2, o3);
            *(float4*)phi = make_float4(o4, o5, o6, o7);
        } else {
            size_t off = (size_t)m*D + n0 + tx*4;
            float4 r0 = *(const float4*)&resid[off];
            float4 r1 = *(const float4*)&resid[off + 64];
            *(float4*)&out[off]      = make_float4(o0+r0.x, o1+r0.y, o2+r0.z, o3+r0.w);
            *(float4*)&out[off + 64] = make_float4(o4+r1.x, o5+r1.y, o6+r1.z, o7+r1.w);
        }
    }
}

// ---------------- clustered attention: 1 block (1024 thr) per (b,h) ----------------
// thread tid owns position s=tid (q row in registers); tids 0,1 also own tail
// positions 1024,1025 via LDS-staged rows. Transposed passes use wave=16 groups,
// lane=dim (coalesced 256B global access).
__launch_bounds__(1024, 4)
__global__ void attn_kernel(const float* __restrict__ q, const float* __restrict__ kk,
                            const float* __restrict__ v, float* __restrict__ o)
{
    __shared__ float At[NC][SEQP];       // 41.3 KB; doubles as part[16][NC][DH]
    __shared__ float cent[NC][DH];       // centroids; later attn-out rows
    __shared__ float tailrow[2][DH];     // q rows 1024/1025, later k rows
    __shared__ float cnorm[NC];
    __shared__ int   cnt[NC];
    __shared__ unsigned char assign[1028];
    __shared__ float redA[16][NC];
    __shared__ float redB[16][NC];
    __shared__ float Mc[NC];
    __shared__ float Sinv[NC];

    const int tid = threadIdx.x;
    const int wv = tid >> 6, lane = tid & 63;
    const int bh = blockIdx.x;
    const int b = bh >> 3, h = bh & 7;
    const float* qh = q  + (size_t)bh * SEQ * DH;
    const float* kh = kk + (size_t)bh * SEQ * DH;
    const float* vh = v  + (size_t)bh * SEQ * DH;
    float* oh = o + (size_t)b * SEQ * D + h * DH;
    float* part = &At[0][0];             // [16][NC][DH] flat: (w*NC+c)*DH+d

    // init: centroids = q[:10]; tail q rows staged to LDS
    if (tid < NC*DH) ((float*)cent)[tid] = qh[tid];
    if (tid >= NC*DH && tid < NC*DH + 2*DH) ((float*)tailrow)[tid - NC*DH] = qh[1024*DH + (tid - NC*DH)];

    // own q row -> registers
    float qr[64];
    {
        const float4* q4 = (const float4*)(qh + (size_t)tid * DH);
        #pragma unroll
        for (int i = 0; i < 16; ++i) *(float4*)&qr[i*4] = q4[i];
    }
    __syncthreads();

    // ---- kmeans: 10 update iters + final assignment ----
    for (int iter = 0; iter <= KITERS; ++iter) {
        if (tid < NC) {
            float sn = 0.f;
            #pragma unroll
            for (int i = 0; i < 16; ++i) {
                float4 cv = *(const float4*)&cent[tid][i*4];
                sn += cv.x*cv.x + cv.y*cv.y + cv.z*cv.z + cv.w*cv.w;
            }
            cnorm[tid] = sn;
            cnt[tid] = 0;
        }
        __syncthreads();

        // assignment (register q vs LDS-broadcast centroids)
        int a_reg;
        {
            int best = 0; float bd = 1e30f;
            #pragma unroll
            for (int c = 0; c < NC; ++c) {
                float acc = 0.f;
                #pragma unroll
                for (int i = 0; i < 16; ++i) {
                    float4 cv = *(const float4*)&cent[c][i*4];
                    acc += qr[i*4]*cv.x + qr[i*4+1]*cv.y + qr[i*4+2]*cv.z + qr[i*4+3]*cv.w;
                }
                float dd = cnorm[c] - 2.f*acc;
                if (dd < bd) { bd = dd; best = c; }
            }
            a_reg = best;
            assign[tid] = (unsigned char)best;
        }
        if (iter < KITERS) {
            #pragma unroll
            for (int c = 0; c < NC; ++c) {
                unsigned long long m = __ballot(a_reg == c);
                if (lane == 0 && m) atomicAdd(&cnt[c], __popcll(m));
            }
        }
        if (tid < 2) {          // tail positions 1024,1025
            int best = 0; float bd = 1e30f;
            #pragma unroll
            for (int c = 0; c < NC; ++c) {
                float acc = 0.f;
                #pragma unroll
                for (int i = 0; i < 64; ++i) acc += tailrow[tid][i]*cent[c][i];
                float dd = cnorm[c] - 2.f*acc;
                if (dd < bd) { bd = dd; best = c; }
            }
            assign[1024 + tid] = (unsigned char)best;
            if (iter < KITERS) atomicAdd(&cnt[best], 1);
        }
        __syncthreads();
        if (iter == KITERS) break;

        // centroid update: wave wv covers s in [wv*64, wv*64+64); coalesced q reads
        {
            float accq[NC];
            #pragma unroll
            for (int c = 0; c < NC; ++c) accq[c] = 0.f;
            const int s0 = wv * 64;
            #pragma unroll 4
            for (int i = 0; i < 64; ++i) {
                int s = s0 + i;
                float qv = qh[(size_t)s*DH + lane];
                int c = assign[s];
                #pragma unroll
                for (int cc = 0; cc < NC; ++cc) accq[cc] += (cc == c) ? qv : 0.f;
            }
            if (wv < 2) {
                int c = assign[1024 + wv];
                float qv = tailrow[wv][lane];
                #pragma unroll
                for (int cc = 0; cc < NC; ++cc) accq[cc] += (cc == c) ? qv : 0.f;
            }
            #pragma unroll
            for (int c = 0; c < NC; ++c) part[(wv*NC + c)*DH + lane] = accq[c];
        }
        __syncthreads();
        if (tid < NC*DH) {
            int c = tid >> 6;
            float s = 0.f;
            #pragma unroll
            for (int w = 0; w < 16; ++w) s += part[w*(NC*DH) + tid];
            ((float*)cent)[tid] = s / fmaxf((float)cnt[c], 1.f);
        }
        __syncthreads();
    }

    // ---- logits: reuse qr registers for k row; tailrow for k tails ----
    if (tid < 2*DH) ((float*)tailrow)[tid] = kh[1024*DH + tid];
    {
        const float4* k4 = (const float4*)(kh + (size_t)tid * DH);
        #pragma unroll
        for (int i = 0; i < 16; ++i) *(float4*)&qr[i*4] = k4[i];
    }
    __syncthreads();

    float lg[NC], lgt[NC];
    #pragma unroll
    for (int c = 0; c < NC; ++c) {
        float acc = 0.f;
        #pragma unroll
        for (int i = 0; i < 16; ++i) {
            float4 cv = *(const float4*)&cent[c][i*4];
            acc += qr[i*4]*cv.x + qr[i*4+1]*cv.y + qr[i*4+2]*cv.z + qr[i*4+3]*cv.w;
        }
        lg[c] = 0.125f * acc;
    }
    if (tid < 2) {
        #pragma unroll
        for (int c = 0; c < NC; ++c) {
            float acc = 0.f;
            #pragma unroll
            for (int i = 0; i < 64; ++i) acc += tailrow[tid][i]*cent[c][i];
            lgt[c] = 0.125f * acc;
        }
    }

    // softmax per cluster row: wave reduce -> 16-way LDS reduce
    #pragma unroll
    for (int c = 0; c < NC; ++c) {
        float m = lg[c];
        if (tid < 2) m = fmaxf(m, lgt[c]);
        #pragma unroll
        for (int off = 32; off; off >>= 1) m = fmaxf(m, __shfl_xor(m, off, 64));
        if (lane == 0) redA[wv][c] = m;
    }
    __syncthreads();
    if (tid < NC) {
        float m = redA[0][tid];
        #pragma unroll
        for (int w = 1; w < 16; ++w) m = fmaxf(m, redA[w][tid]);
        Mc[tid] = m;
    }
    __syncthreads();
    #pragma unroll
    for (int c = 0; c < NC; ++c) lg[c] = expf(lg[c] - Mc[c]);
    if (tid < 2) {
        #pragma unroll
        for (int c = 0; c < NC; ++c) lgt[c] = expf(lgt[c] - Mc[c]);
    }
    #pragma unroll
    for (int c = 0; c < NC; ++c) {
        float s = lg[c] + ((tid < 2) ? lgt[c] : 0.f);
        #pragma unroll
        for (int off = 32; off; off >>= 1) s += __shfl_xor(s, off, 64);
        if (lane == 0) redB[wv][c] = s;
    }
    __syncthreads();
    if (tid < NC) {
        float s = 0.f;
        #pragma unroll
        for (int w = 0; w < 16; ++w) s += redB[w][tid];
        Sinv[tid] = 1.f / s;
    }
    __syncthreads();
    #pragma unroll
    for (int c = 0; c < NC; ++c) At[c][tid] = lg[c] * Sinv[c];
    if (tid < 2) {
        #pragma unroll
        for (int c = 0; c < NC; ++c) At[c][1024 + tid] = lgt[c] * Sinv[c];
    }
    __syncthreads();

    // ---- A @ v: transposed, coalesced v reads, wave partials ----
    {
        float accv[NC];
        #pragma unroll
        for (int c = 0; c < NC; ++c) accv[c] = 0.f;
        const int s0 = wv * 64;
        for (int i = 0; i < 64; i += 4) {
            float vv0 = vh[(size_t)(s0+i  )*DH + lane];
            float vv1 = vh[(size_t)(s0+i+1)*DH + lane];
            float vv2 = vh[(size_t)(s0+i+2)*DH + lane];
            float vv3 = vh[(size_t)(s0+i+3)*DH + lane];
            #pragma unroll
            for (int c = 0; c < NC; ++c) {
                float4 av = *(const float4*)&At[c][s0+i];
                accv[c] += av.x*vv0 + av.y*vv1 + av.z*vv2 + av.w*vv3;
            }
        }
        if (wv < 2) {
            int s = 1024 + wv;
            float vv = vh[(size_t)s*DH + lane];
            #pragma unroll
            for (int c = 0; c < NC; ++c) accv[c] += At[c][s] * vv;
        }
        __syncthreads();   // all At reads done before part (same memory) is written
        #pragma unroll
        for (int c = 0; c < NC; ++c) part[(wv*NC + c)*DH + lane] = accv[c];
    }
    __syncthreads();
    if (tid < NC*DH) {     // reduce into cent (reused as attn-out rows)
        float s = 0.f;
        #pragma unroll
        for (int w = 0; w < 16; ++w) s += part[w*(NC*DH) + tid];
        ((float*)cent)[tid] = s;
    }
    __syncthreads();

    // ---- gather rows to output (coalesced 256B stores) ----
    {
        const int s0 = wv * 64;
        for (int i = 0; i < 64; ++i) {
            int s = s0 + i;
            oh[(size_t)s*D + lane] = cent[assign[s]][lane];
        }
        if (wv < 2) {
            int s = 1024 + wv;
            oh[(size_t)s*D + lane] = cent[assign[s]][lane];
        }
    }
}

// ---------------- fused LN1 + FFN + residual + LN2, one block per row ----------------
__launch_bounds__(256)
__global__ void ffn_ln_kernel(const float* __restrict__ in, float* __restrict__ z,
    const float* __restrict__ g1, const float* __restrict__ c1,
    const float* __restrict__ W1, const float* __restrict__ b1,
    const float* __restrict__ W2, const float* __restrict__ b2,
    const float* __restrict__ g2, const float* __restrict__ c2)
{
    __shared__ float red[8];
    __shared__ float redh[4][DFF];
    const int row = blockIdx.x, tid = threadIdx.x;
    const int lane = tid & 63, wid = tid >> 6;
    const float* r = in + (size_t)row * D;
    float x0 = r[tid], x1 = r[tid + 256];
    float s = x0 + x1, ss = x0*x0 + x1*x1;
    #pragma unroll
    for (int off = 32; off; off >>= 1) {
        s  += __shfl_xor(s,  off, 64);
        ss += __shfl_xor(ss, off, 64);
    }
    if (lane == 0) { red[wid] = s; red[4 + wid] = ss; }
    __syncthreads();
    float tot  = red[0] + red[1] + red[2] + red[3];
    float tot2 = red[4] + red[5] + red[6] + red[7];
    float mean = tot * (1.f/512.f);
    float var  = tot2 * (1.f/512.f) - mean*mean;
    float rstd = rsqrtf(var + 1e-5f);
    float za = (x0 - mean)*rstd*g1[tid]       + c1[tid];
    float zb = (x1 - mean)*rstd*g1[tid + 256] + c1[tid + 256];

    float p[DFF];
    #pragma unroll
    for (int j = 0; j < DFF; ++j)
        p[j] = za * W1[(size_t)tid*DFF + j] + zb * W1[(size_t)(tid+256)*DFF + j];
    #pragma unroll
    for (int off = 32; off; off >>= 1)
        #pragma unroll
        for (int j = 0; j < DFF; ++j) p[j] += __shfl_xor(p[j], off, 64);
    if (lane == 0) {
        #pragma unroll
        for (int j = 0; j < DFF; ++j) redh[wid][j] = p[j];
    }
    __syncthreads();
    float hv[DFF];
    #pragma unroll
    for (int j = 0; j < DFF; ++j)
        hv[j] = fmaxf(redh[0][j] + redh[1][j] + redh[2][j] + redh[3][j] + b1[j], 0.f);
    float y0 = b2[tid], y1 = b2[tid + 256];
    #pragma unroll
    for (int j = 0; j < DFF; ++j) {
        y0 += hv[j] * W2[(size_t)j*D + tid];
        y1 += hv[j] * W2[(size_t)j*D + tid + 256];
    }
    float t0 = za + y0, t1 = zb + y1;
    float s2 = t0 + t1, ss2 = t0*t0 + t1*t1;
    #pragma unroll
    for (int off = 32; off; off >>= 1) {
        s2  += __shfl_xor(s2,  off, 64);
        ss2 += __shfl_xor(ss2, off, 64);
    }
    if (lane == 0) { red[wid] = s2; red[4 + wid] = ss2; }
    __syncthreads();
    float tt  = red[0] + red[1] + red[2] + red[3];
    float tt2 = red[4] + red[5] + red[6] + red[7];
    float m2 = tt * (1.f/512.f);
    float v2 = tt2 * (1.f/512.f) - m2*m2;
    float rstd2 = rsqrtf(v2 + 1e-5f);
    float* zo = z + (size_t)row * D;
    zo[tid]       = (t0 - m2)*rstd2*g2[tid]       + c2[tid];
    zo[tid + 256] = (t1 - m2)*rstd2*g2[tid + 256] + c2[tid + 256];
}

// ---------------- extract mu / logvar ----------------
__launch_bounds__(256)
__global__ void extract_kernel(const float* __restrict__ z, float* __restrict__ out) {
    int i = blockIdx.x * 256 + threadIdx.x;
    if (i >= 2*BATCH*D) return;
    int half = i >> 13;
    int j = i & 8191;
    int b = j >> 9, d = j & 511;
    out[i] = z[((size_t)b*SEQ + half)*D + d];
}

extern "C" void kernel_launch(void* const* d_in, const int* in_sizes, int n_in,
                              void* d_out, int out_size, void* d_ws, size_t ws_size,
                              hipStream_t stream)
{
    const float* x      = (const float*)d_in[0];
    const int*   y      = (const int*)  d_in[1];
    const float* muQ    = (const float*)d_in[3];
    const float* sigQ   = (const float*)d_in[4];
    const float* mu_w   = (const float*)d_in[5];
    const float* mu_b   = (const float*)d_in[6];
    const float* sig_w  = (const float*)d_in[7];
    const float* sig_b  = (const float*)d_in[8];
    const float* skel_w = (const float*)d_in[9];
    const float* skel_b = (const float*)d_in[10];
    const float* Wq     = (const float*)d_in[11];
    const float* bq     = (const float*)d_in[12];
    const float* Wk     = (const float*)d_in[13];
    const float* bk     = (const float*)d_in[14];
    const float* Wv     = (const float*)d_in[15];
    const float* bv     = (const float*)d_in[16];
    const float* Wo     = (const float*)d_in[17];
    const float* bo     = (const float*)d_in[18];
    const float* g1     = (const float*)d_in[19];
    const float* c1     = (const float*)d_in[20];
    const float* g2     = (const float*)d_in[21];
    const float* c2     = (const float*)d_in[22];
    const float* W1     = (const float*)d_in[23];
    const float* b1     = (const float*)d_in[24];
    const float* W2     = (const float*)d_in[25];
    const float* b2     = (const float*)d_in[26];

    float* z  = (float*)d_ws;
    float* ob = z  + NBUF;   // attention output (B,S,D); also o-proj input
    float* qb = ob + NBUF;   // q (B*H,S,DH); reused as o-proj output
    float* kb = qb + NBUF;
    float* vb = kb + NBUF;

    embed_kernel<<<dim3(258, BATCH), 256, 0, stream>>>(
        x, y, muQ, sigQ, mu_w, mu_b, sig_w, sig_b, skel_w, skel_b, z);

    dim3 ggrid(4, 129);
    for (int l = 0; l < NLAYERS; ++l) {
        gemm512<0><<<ggrid, 256, 0, stream>>>(z, Wq + (size_t)l*D*D, bq + l*D, nullptr, qb, MR);
        gemm512<0><<<ggrid, 256, 0, stream>>>(z, Wk + (size_t)l*D*D, bk + l*D, nullptr, kb, MR);
        gemm512<0><<<ggrid, 256, 0, stream>>>(z, Wv + (size_t)l*D*D, bv + l*D, nullptr, vb, MR);
        attn_kernel<<<BATCH*H, 1024, 0, stream>>>(qb, kb, vb, ob);
        gemm512<1><<<ggrid, 256, 0, stream>>>(ob, Wo + (size_t)l*D*D, bo + l*D, z, qb, MR);
        ffn_ln_kernel<<<MR, 256, 0, stream>>>(qb, z,
            g1 + (size_t)l*D, c1 + (size_t)l*D,
            W1 + (size_t)l*D*DFF, b1 + (size_t)l*DFF,
            W2 + (size_t)l*DFF*D, b2 + (size_t)l*D,
            g2 + (size_t)l*D, c2 + (size_t)l*D);
    }
    extract_kernel<<<64, 256, 0, stream>>>(z, (float*)d_out);

    (void)in_sizes; (void)n_in; (void)out_size; (void)ws_size;
}

// Round 3
// 9955.931 us; speedup vs baseline: 1.1667x; 1.0028x over previous
//
#include <hip/hip_runtime.h>
#include <math.h>

#define D 512
#define H 8
#define DH 64
#define NLAYERS 8
#define DFF 8
#define NC 10
#define KITERS 10
#define SEQ 1026
#define SEQP 1032
#define BATCH 16
#define MR (BATCH*SEQ)            // 16416 rows
#define NBUF ((size_t)MR * D)     // floats per big buffer

__device__ __forceinline__ float pe_val(int s, int d) {
    float e = (float)(d & ~1);
    float dv = expf(e * (-9.210340371976184f / 512.0f));   // ln(10000)/512
    float ph = (float)s * dv;
    return (d & 1) ? cosf(ph) : sinf(ph);
}

// ---------------- embed ----------------
__launch_bounds__(256)
__global__ void embed_kernel(const float* __restrict__ x, const int* __restrict__ y,
    const float* __restrict__ muQ, const float* __restrict__ sigQ,
    const float* __restrict__ mu_w, const float* __restrict__ mu_b,
    const float* __restrict__ sig_w, const float* __restrict__ sig_b,
    const float* __restrict__ skel_w, const float* __restrict__ skel_b,
    float* __restrict__ z)
{
    __shared__ float xin[3072];
    const int bx = blockIdx.x, b = blockIdx.y, tid = threadIdx.x;
    if (bx < 2) {
        const float* Q  = (bx == 0) ? muQ  : sigQ;
        const float* W  = (bx == 0) ? mu_w : sig_w;
        const float* bb = (bx == 0) ? mu_b : sig_b;
        for (int i = tid; i < 3072; i += 256) {
            int a = y[b*6 + (i >> 9)];
            xin[i] = Q[a*D + (i & 511)];
        }
        __syncthreads();
        const int d0 = tid, d1 = tid + 256;
        float acc0 = bb[d0], acc1 = bb[d1];
        const float4* x4 = (const float4*)xin;
        for (int i4 = 0; i4 < 768; ++i4) {
            float4 xv = x4[i4];
            int r = i4 * 4;
            acc0 += xv.x*W[(size_t)(r+0)*D+d0] + xv.y*W[(size_t)(r+1)*D+d0]
                  + xv.z*W[(size_t)(r+2)*D+d0] + xv.w*W[(size_t)(r+3)*D+d0];
            acc1 += xv.x*W[(size_t)(r+0)*D+d1] + xv.y*W[(size_t)(r+1)*D+d1]
                  + xv.z*W[(size_t)(r+2)*D+d1] + xv.w*W[(size_t)(r+3)*D+d1];
        }
        size_t base = ((size_t)b*SEQ + bx) * D;
        z[base + d0] = acc0 + pe_val(bx, d0);
        z[base + d1] = acc1 + pe_val(bx, d1);
    } else {
        const int f0 = (bx - 2) * 4;
        for (int idx = tid; idx < 600; idx += 256) {
            int i = idx >> 2, ff = idx & 3;
            xin[idx] = x[((size_t)(b*150 + i))*1024 + f0 + ff];
        }
        __syncthreads();
        const float4* x4 = (const float4*)xin;
        for (int dd = 0; dd < 2; ++dd) {
            const int d = tid + dd*256;
            float a0, a1, a2, a3;
            a0 = a1 = a2 = a3 = skel_b[d];
            for (int i = 0; i < 150; ++i) {
                float4 xv = x4[i];
                float w = skel_w[(size_t)i*D + d];
                a0 += xv.x*w; a1 += xv.y*w; a2 += xv.z*w; a3 += xv.w*w;
            }
            float a[4] = {a0, a1, a2, a3};
            #pragma unroll
            for (int ff = 0; ff < 4; ++ff) {
                int s = f0 + ff + 2;
                z[((size_t)b*SEQ + s)*D + d] = a[ff] + pe_val(s, d);
            }
        }
    }
}

// ---------------- GEMM (M x 512) @ (512 x 512) ----------------
__device__ __forceinline__ float4 ld_guard(const float* A, int m, int kcol, int M) {
    if (m < M) return *(const float4*)&A[(size_t)m*D + kcol];
    return make_float4(0.f, 0.f, 0.f, 0.f);
}

template<int EPI>
__launch_bounds__(256, 2)
__global__ void gemm512(const float* __restrict__ A, const float* __restrict__ W,
                        const float* __restrict__ bias, const float* __restrict__ resid,
                        float* __restrict__ out, int M)
{
    __shared__ float As[16*132];
    __shared__ float Bs[16*132];
    const int tid = threadIdx.x;
    const int tx = tid & 15, ty = tid >> 4;
    const int m0 = blockIdx.y * 128, n0 = blockIdx.x * 128;
    const int ar = tid >> 2, ac = (tid & 3) * 4;
    const int bkr = tid >> 5, bqc = (tid & 31) * 4;

    float acc[8][8];
    #pragma unroll
    for (int i = 0; i < 8; ++i)
        #pragma unroll
        for (int j = 0; j < 8; ++j) acc[i][j] = 0.f;

    for (int kt = 0; kt < 32; ++kt) {
        const int kb = kt * 16;
        float4 a0 = ld_guard(A, m0 + ar,      kb + ac, M);
        float4 a1 = ld_guard(A, m0 + ar + 64, kb + ac, M);
        float4 b0 = *(const float4*)&W[(size_t)(kb + bkr    )*D + n0 + bqc];
        float4 b1 = *(const float4*)&W[(size_t)(kb + bkr + 8)*D + n0 + bqc];
        if (kt) __syncthreads();
        As[(ac+0)*132 + ar] = a0.x; As[(ac+1)*132 + ar] = a0.y;
        As[(ac+2)*132 + ar] = a0.z; As[(ac+3)*132 + ar] = a0.w;
        As[(ac+0)*132 + ar + 64] = a1.x; As[(ac+1)*132 + ar + 64] = a1.y;
        As[(ac+2)*132 + ar + 64] = a1.z; As[(ac+3)*132 + ar + 64] = a1.w;
        *(float4*)&Bs[bkr*132 + bqc] = b0;
        *(float4*)&Bs[(bkr+8)*132 + bqc] = b1;
        __syncthreads();
        #pragma unroll
        for (int k = 0; k < 16; ++k) {
            float4 alo = *(const float4*)&As[k*132 + ty*4];
            float4 ahi = *(const float4*)&As[k*132 + 64 + ty*4];
            float4 blo = *(const float4*)&Bs[k*132 + tx*4];
            float4 bhi = *(const float4*)&Bs[k*132 + 64 + tx*4];
            float av[8] = {alo.x, alo.y, alo.z, alo.w, ahi.x, ahi.y, ahi.z, ahi.w};
            float bv[8] = {blo.x, blo.y, blo.z, blo.w, bhi.x, bhi.y, bhi.z, bhi.w};
            #pragma unroll
            for (int i = 0; i < 8; ++i)
                #pragma unroll
                for (int j = 0; j < 8; ++j) acc[i][j] += av[i] * bv[j];
        }
    }

    float4 blo = *(const float4*)&bias[n0 + tx*4];
    float4 bhi = *(const float4*)&bias[n0 + 64 + tx*4];
    #pragma unroll
    for (int i = 0; i < 8; ++i) {
        int m = m0 + ((i >> 2) << 6) + ty*4 + (i & 3);
        if (m >= M) continue;
        float o0 = acc[i][0] + blo.x, o1 = acc[i][1] + blo.y;
        float o2 = acc[i][2] + blo.z, o3 = acc[i][3] + blo.w;
        float o4 = acc[i][4] + bhi.x, o5 = acc[i][5] + bhi.y;
        float o6 = acc[i][6] + bhi.z, o7 = acc[i][7] + bhi.w;
        if (EPI == 0) {
            int bb = m / SEQ;
            int ss = m - bb * SEQ;
            int nlo = n0 + tx*4, nhi = nlo + 64;
            float* plo = out + ((size_t)(bb*H + (nlo >> 6)))*((size_t)SEQ*DH) + (size_t)ss*DH + (nlo & 63);
            float* phi = out + ((size_t)(bb*H + (nhi >> 6)))*((size_t)SEQ*DH) + (size_t)ss*DH + (nhi & 63);
            *(float4*)plo = make_float4(o0, o1, o2, o3);
            *(float4*)phi = make_float4(o4, o5, o6, o7);
        } else {
            size_t off = (size_t)m*D + n0 + tx*4;
            float4 r0 = *(const float4*)&resid[off];
            float4 r1 = *(const float4*)&resid[off + 64];
            *(float4*)&out[off]      = make_float4(o0+r0.x, o1+r0.y, o2+r0.z, o3+r0.w);
            *(float4*)&out[off + 64] = make_float4(o4+r1.x, o5+r1.y, o6+r1.z, o7+r1.w);
        }
    }
}

// ---------------- clustered attention: 1 block (1024 thr) per (b,h) ----------------
// q row lives in float4 qr4[16] with compile-time-constant indices ONLY
// (a float[64] with reinterpret-casts was sent to scratch by the compiler:
//  VGPR_Count=64 + 377MB WRITE_SIZE in round 2).
__launch_bounds__(1024, 4)
__global__ void attn_kernel(const float* __restrict__ q, const float* __restrict__ kk,
                            const float* __restrict__ v, float* __restrict__ o)
{
    __shared__ float At[NC][SEQP];       // 41.3 KB; doubles as part[16][NC][DH]
    __shared__ float cent[NC][DH];       // centroids; later attn-out rows
    __shared__ float tailrow[2][DH];     // q rows 1024/1025, later k rows
    __shared__ float cnorm[NC];
    __shared__ int   cnt[NC];
    __shared__ unsigned char assign[1028];
    __shared__ float redA[16][NC];
    __shared__ float redB[16][NC];
    __shared__ float Mc[NC];
    __shared__ float Sinv[NC];

    const int tid = threadIdx.x;
    const int wv = tid >> 6, lane = tid & 63;
    const int bh = blockIdx.x;
    const int b = bh >> 3, h = bh & 7;
    const float* qh = q  + (size_t)bh * SEQ * DH;
    const float* kh = kk + (size_t)bh * SEQ * DH;
    const float* vh = v  + (size_t)bh * SEQ * DH;
    float* oh = o + (size_t)b * SEQ * D + h * DH;
    float* part = &At[0][0];             // [16][NC][DH] flat: (w*NC+c)*DH+d

    // init: centroids = q[:10]; tail q rows staged to LDS
    if (tid < NC*DH) ((float*)cent)[tid] = qh[tid];
    if (tid >= NC*DH && tid < NC*DH + 2*DH) ((float*)tailrow)[tid - NC*DH] = qh[1024*DH + (tid - NC*DH)];

    // own q row -> registers (constant-indexed float4s; no address-taken array)
    float4 qr4[16];
    {
        const float4* q4 = (const float4*)(qh + (size_t)tid * DH);
        #pragma unroll
        for (int i = 0; i < 16; ++i) qr4[i] = q4[i];
    }
    __syncthreads();

    // ---- kmeans: 10 update iters + final assignment ----
    for (int iter = 0; iter <= KITERS; ++iter) {
        if (tid < NC) {
            float sn = 0.f;
            #pragma unroll
            for (int i = 0; i < 16; ++i) {
                float4 cv = *(const float4*)&cent[tid][i*4];
                sn += cv.x*cv.x + cv.y*cv.y + cv.z*cv.z + cv.w*cv.w;
            }
            cnorm[tid] = sn;
            cnt[tid] = 0;
        }
        __syncthreads();

        // assignment (register q vs LDS-broadcast centroids)
        int a_reg;
        {
            int best = 0; float bd = 1e30f;
            #pragma unroll
            for (int c = 0; c < NC; ++c) {
                float acc = 0.f;
                #pragma unroll
                for (int i = 0; i < 16; ++i) {
                    float4 cv = *(const float4*)&cent[c][i*4];
                    acc += qr4[i].x*cv.x + qr4[i].y*cv.y + qr4[i].z*cv.z + qr4[i].w*cv.w;
                }
                float dd = cnorm[c] - 2.f*acc;
                if (dd < bd) { bd = dd; best = c; }
            }
            a_reg = best;
            assign[tid] = (unsigned char)best;
        }
        if (iter < KITERS) {
            #pragma unroll
            for (int c = 0; c < NC; ++c) {
                unsigned long long m = __ballot(a_reg == c);
                if (lane == 0 && m) atomicAdd(&cnt[c], __popcll(m));
            }
        }
        if (tid < 2) {          // tail positions 1024,1025
            int best = 0; float bd = 1e30f;
            #pragma unroll
            for (int c = 0; c < NC; ++c) {
                float acc = 0.f;
                #pragma unroll
                for (int i = 0; i < 64; ++i) acc += tailrow[tid][i]*cent[c][i];
                float dd = cnorm[c] - 2.f*acc;
                if (dd < bd) { bd = dd; best = c; }
            }
            assign[1024 + tid] = (unsigned char)best;
            if (iter < KITERS) atomicAdd(&cnt[best], 1);
        }
        __syncthreads();
        if (iter == KITERS) break;

        // centroid update: wave wv covers s in [wv*64, wv*64+64); coalesced q reads
        {
            float accq[NC];
            #pragma unroll
            for (int c = 0; c < NC; ++c) accq[c] = 0.f;
            const int s0 = wv * 64;
            #pragma unroll 4
            for (int i = 0; i < 64; ++i) {
                int s = s0 + i;
                float qv = qh[(size_t)s*DH + lane];
                int c = assign[s];
                #pragma unroll
                for (int cc = 0; cc < NC; ++cc) accq[cc] += (cc == c) ? qv : 0.f;
            }
            if (wv < 2) {
                int c = assign[1024 + wv];
                float qv = tailrow[wv][lane];
                #pragma unroll
                for (int cc = 0; cc < NC; ++cc) accq[cc] += (cc == c) ? qv : 0.f;
            }
            #pragma unroll
            for (int c = 0; c < NC; ++c) part[(wv*NC + c)*DH + lane] = accq[c];
        }
        __syncthreads();
        if (tid < NC*DH) {
            int c = tid >> 6;
            float s = 0.f;
            #pragma unroll
            for (int w = 0; w < 16; ++w) s += part[w*(NC*DH) + tid];
            ((float*)cent)[tid] = s / fmaxf((float)cnt[c], 1.f);
        }
        __syncthreads();
    }

    // ---- logits: reuse qr4 registers for k row; tailrow for k tails ----
    if (tid < 2*DH) ((float*)tailrow)[tid] = kh[1024*DH + tid];
    {
        const float4* k4 = (const float4*)(kh + (size_t)tid * DH);
        #pragma unroll
        for (int i = 0; i < 16; ++i) qr4[i] = k4[i];
    }
    __syncthreads();

    float lg[NC], lgt[NC];
    #pragma unroll
    for (int c = 0; c < NC; ++c) {
        float acc = 0.f;
        #pragma unroll
        for (int i = 0; i < 16; ++i) {
            float4 cv = *(const float4*)&cent[c][i*4];
            acc += qr4[i].x*cv.x + qr4[i].y*cv.y + qr4[i].z*cv.z + qr4[i].w*cv.w;
        }
        lg[c] = 0.125f * acc;
    }
    if (tid < 2) {
        #pragma unroll
        for (int c = 0; c < NC; ++c) {
            float acc = 0.f;
            #pragma unroll
            for (int i = 0; i < 64; ++i) acc += tailrow[tid][i]*cent[c][i];
            lgt[c] = 0.125f * acc;
        }
    }

    // softmax per cluster row: wave reduce -> 16-way LDS reduce
    #pragma unroll
    for (int c = 0; c < NC; ++c) {
        float m = lg[c];
        if (tid < 2) m = fmaxf(m, lgt[c]);
        #pragma unroll
        for (int off = 32; off; off >>= 1) m = fmaxf(m, __shfl_xor(m, off, 64));
        if (lane == 0) redA[wv][c] = m;
    }
    __syncthreads();
    if (tid < NC) {
        float m = redA[0][tid];
        #pragma unroll
        for (int w = 1; w < 16; ++w) m = fmaxf(m, redA[w][tid]);
        Mc[tid] = m;
    }
    __syncthreads();
    #pragma unroll
    for (int c = 0; c < NC; ++c) lg[c] = expf(lg[c] - Mc[c]);
    if (tid < 2) {
        #pragma unroll
        for (int c = 0; c < NC; ++c) lgt[c] = expf(lgt[c] - Mc[c]);
    }
    #pragma unroll
    for (int c = 0; c < NC; ++c) {
        float s = lg[c] + ((tid < 2) ? lgt[c] : 0.f);
        #pragma unroll
        for (int off = 32; off; off >>= 1) s += __shfl_xor(s, off, 64);
        if (lane == 0) redB[wv][c] = s;
    }
    __syncthreads();
    if (tid < NC) {
        float s = 0.f;
        #pragma unroll
        for (int w = 0; w < 16; ++w) s += redB[w][tid];
        Sinv[tid] = 1.f / s;
    }
    __syncthreads();
    #pragma unroll
    for (int c = 0; c < NC; ++c) At[c][tid] = lg[c] * Sinv[c];
    if (tid < 2) {
        #pragma unroll
        for (int c = 0; c < NC; ++c) At[c][1024 + tid] = lgt[c] * Sinv[c];
    }
    __syncthreads();

    // ---- A @ v: transposed, coalesced v reads, wave partials ----
    {
        float accv[NC];
        #pragma unroll
        for (int c = 0; c < NC; ++c) accv[c] = 0.f;
        const int s0 = wv * 64;
        for (int i = 0; i < 64; i += 4) {
            float vv0 = vh[(size_t)(s0+i  )*DH + lane];
            float vv1 = vh[(size_t)(s0+i+1)*DH + lane];
            float vv2 = vh[(size_t)(s0+i+2)*DH + lane];
            float vv3 = vh[(size_t)(s0+i+3)*DH + lane];
            #pragma unroll
            for (int c = 0; c < NC; ++c) {
                float4 av = *(const float4*)&At[c][s0+i];
                accv[c] += av.x*vv0 + av.y*vv1 + av.z*vv2 + av.w*vv3;
            }
        }
        if (wv < 2) {
            int s = 1024 + wv;
            float vv = vh[(size_t)s*DH + lane];
            #pragma unroll
            for (int c = 0; c < NC; ++c) accv[c] += At[c][s] * vv;
        }
        __syncthreads();   // all At reads done before part (same memory) is written
        #pragma unroll
        for (int c = 0; c < NC; ++c) part[(wv*NC + c)*DH + lane] = accv[c];
    }
    __syncthreads();
    if (tid < NC*DH) {     // reduce into cent (reused as attn-out rows)
        float s = 0.f;
        #pragma unroll
        for (int w = 0; w < 16; ++w) s += part[w*(NC*DH) + tid];
        ((float*)cent)[tid] = s;
    }
    __syncthreads();

    // ---- gather rows to output (coalesced 256B stores) ----
    {
        const int s0 = wv * 64;
        for (int i = 0; i < 64; ++i) {
            int s = s0 + i;
            oh[(size_t)s*D + lane] = cent[assign[s]][lane];
        }
        if (wv < 2) {
            int s = 1024 + wv;
            oh[(size_t)s*D + lane] = cent[assign[s]][lane];
        }
    }
}

// ---------------- fused LN1 + FFN + residual + LN2, one block per row ----------------
__launch_bounds__(256)
__global__ void ffn_ln_kernel(const float* __restrict__ in, float* __restrict__ z,
    const float* __restrict__ g1, const float* __restrict__ c1,
    const float* __restrict__ W1, const float* __restrict__ b1,
    const float* __restrict__ W2, const float* __restrict__ b2,
    const float* __restrict__ g2, const float* __restrict__ c2)
{
    __shared__ float red[8];
    __shared__ float redh[4][DFF];
    const int row = blockIdx.x, tid = threadIdx.x;
    const int lane = tid & 63, wid = tid >> 6;
    const float* r = in + (size_t)row * D;
    float x0 = r[tid], x1 = r[tid + 256];
    float s = x0 + x1, ss = x0*x0 + x1*x1;
    #pragma unroll
    for (int off = 32; off; off >>= 1) {
        s  += __shfl_xor(s,  off, 64);
        ss += __shfl_xor(ss, off, 64);
    }
    if (lane == 0) { red[wid] = s; red[4 + wid] = ss; }
    __syncthreads();
    float tot  = red[0] + red[1] + red[2] + red[3];
    float tot2 = red[4] + red[5] + red[6] + red[7];
    float mean = tot * (1.f/512.f);
    float var  = tot2 * (1.f/512.f) - mean*mean;
    float rstd = rsqrtf(var + 1e-5f);
    float za = (x0 - mean)*rstd*g1[tid]       + c1[tid];
    float zb = (x1 - mean)*rstd*g1[tid + 256] + c1[tid + 256];

    float p[DFF];
    #pragma unroll
    for (int j = 0; j < DFF; ++j)
        p[j] = za * W1[(size_t)tid*DFF + j] + zb * W1[(size_t)(tid+256)*DFF + j];
    #pragma unroll
    for (int off = 32; off; off >>= 1)
        #pragma unroll
        for (int j = 0; j < DFF; ++j) p[j] += __shfl_xor(p[j], off, 64);
    if (lane == 0) {
        #pragma unroll
        for (int j = 0; j < DFF; ++j) redh[wid][j] = p[j];
    }
    __syncthreads();
    float hv[DFF];
    #pragma unroll
    for (int j = 0; j < DFF; ++j)
        hv[j] = fmaxf(redh[0][j] + redh[1][j] + redh[2][j] + redh[3][j] + b1[j], 0.f);
    float y0 = b2[tid], y1 = b2[tid + 256];
    #pragma unroll
    for (int j = 0; j < DFF; ++j) {
        y0 += hv[j] * W2[(size_t)j*D + tid];
        y1 += hv[j] * W2[(size_t)j*D + tid + 256];
    }
    float t0 = za + y0, t1 = zb + y1;
    float s2 = t0 + t1, ss2 = t0*t0 + t1*t1;
    #pragma unroll
    for (int off = 32; off; off >>= 1) {
        s2  += __shfl_xor(s2,  off, 64);
        ss2 += __shfl_xor(ss2, off, 64);
    }
    if (lane == 0) { red[wid] = s2; red[4 + wid] = ss2; }
    __syncthreads();
    float tt  = red[0] + red[1] + red[2] + red[3];
    float tt2 = red[4] + red[5] + red[6] + red[7];
    float m2 = tt * (1.f/512.f);
    float v2 = tt2 * (1.f/512.f) - m2*m2;
    float rstd2 = rsqrtf(v2 + 1e-5f);
    float* zo = z + (size_t)row * D;
    zo[tid]       = (t0 - m2)*rstd2*g2[tid]       + c2[tid];
    zo[tid + 256] = (t1 - m2)*rstd2*g2[tid + 256] + c2[tid + 256];
}

// ---------------- extract mu / logvar ----------------
__launch_bounds__(256)
__global__ void extract_kernel(const float* __restrict__ z, float* __restrict__ out) {
    int i = blockIdx.x * 256 + threadIdx.x;
    if (i >= 2*BATCH*D) return;
    int half = i >> 13;
    int j = i & 8191;
    int b = j >> 9, d = j & 511;
    out[i] = z[((size_t)b*SEQ + half)*D + d];
}

extern "C" void kernel_launch(void* const* d_in, const int* in_sizes, int n_in,
                              void* d_out, int out_size, void* d_ws, size_t ws_size,
                              hipStream_t stream)
{
    const float* x      = (const float*)d_in[0];
    const int*   y      = (const int*)  d_in[1];
    const float* muQ    = (const float*)d_in[3];
    const float* sigQ   = (const float*)d_in[4];
    const float* mu_w   = (const float*)d_in[5];
    const float* mu_b   = (const float*)d_in[6];
    const float* sig_w  = (const float*)d_in[7];
    const float* sig_b  = (const float*)d_in[8];
    const float* skel_w = (const float*)d_in[9];
    const float* skel_b = (const float*)d_in[10];
    const float* Wq     = (const float*)d_in[11];
    const float* bq     = (const float*)d_in[12];
    const float* Wk     = (const float*)d_in[13];
    const float* bk     = (const float*)d_in[14];
    const float* Wv     = (const float*)d_in[15];
    const float* bv     = (const float*)d_in[16];
    const float* Wo     = (const float*)d_in[17];
    const float* bo     = (const float*)d_in[18];
    const float* g1     = (const float*)d_in[19];
    const float* c1     = (const float*)d_in[20];
    const float* g2     = (const float*)d_in[21];
    const float* c2     = (const float*)d_in[22];
    const float* W1     = (const float*)d_in[23];
    const float* b1     = (const float*)d_in[24];
    const float* W2     = (const float*)d_in[25];
    const float* b2     = (const float*)d_in[26];

    float* z  = (float*)d_ws;
    float* ob = z  + NBUF;   // attention output (B,S,D); also o-proj input
    float* qb = ob + NBUF;   // q (B*H,S,DH); reused as o-proj output
    float* kb = qb + NBUF;
    float* vb = kb + NBUF;

    embed_kernel<<<dim3(258, BATCH), 256, 0, stream>>>(
        x, y, muQ, sigQ, mu_w, mu_b, sig_w, sig_b, skel_w, skel_b, z);

    dim3 ggrid(4, 129);
    for (int l = 0; l < NLAYERS; ++l) {
        gemm512<0><<<ggrid, 256, 0, stream>>>(z, Wq + (size_t)l*D*D, bq + l*D, nullptr, qb, MR);
        gemm512<0><<<ggrid, 256, 0, stream>>>(z, Wk + (size_t)l*D*D, bk + l*D, nullptr, kb, MR);
        gemm512<0><<<ggrid, 256, 0, stream>>>(z, Wv + (size_t)l*D*D, bv + l*D, nullptr, vb, MR);
        attn_kernel<<<BATCH*H, 1024, 0, stream>>>(qb, kb, vb, ob);
        gemm512<1><<<ggrid, 256, 0, stream>>>(ob, Wo + (size_t)l*D*D, bo + l*D, z, qb, MR);
        ffn_ln_kernel<<<MR, 256, 0, stream>>>(qb, z,
            g1 + (size_t)l*D, c1 + (size_t)l*D,
            W1 + (size_t)l*D*DFF, b1 + (size_t)l*DFF,
            W2 + (size_t)l*DFF*D, b2 + (size_t)l*D,
            g2 + (size_t)l*D, c2 + (size_t)l*D);
    }
    extract_kernel<<<64, 256, 0, stream>>>(z, (float*)d_out);

    (void)in_sizes; (void)n_in; (void)out_size; (void)ws_size;
}

// Round 4
// 9601.234 us; speedup vs baseline: 1.2098x; 1.0369x over previous
//
#include <hip/hip_runtime.h>
#include <math.h>

#define D 512
#define H 8
#define DH 64
#define NLAYERS 8
#define DFF 8
#define NC 10
#define KITERS 10
#define SEQ 1026
#define SEQP 1032
#define BATCH 16
#define MR (BATCH*SEQ)            // 16416 rows
#define NBUF ((size_t)MR * D)     // floats per big buffer

__device__ __forceinline__ float pe_val(int s, int d) {
    float e = (float)(d & ~1);
    float dv = expf(e * (-9.210340371976184f / 512.0f));   // ln(10000)/512
    float ph = (float)s * dv;
    return (d & 1) ? cosf(ph) : sinf(ph);
}

// ---------------- embed ----------------
__launch_bounds__(256)
__global__ void embed_kernel(const float* __restrict__ x, const int* __restrict__ y,
    const float* __restrict__ muQ, const float* __restrict__ sigQ,
    const float* __restrict__ mu_w, const float* __restrict__ mu_b,
    const float* __restrict__ sig_w, const float* __restrict__ sig_b,
    const float* __restrict__ skel_w, const float* __restrict__ skel_b,
    float* __restrict__ z)
{
    __shared__ float xin[3072];
    const int bx = blockIdx.x, b = blockIdx.y, tid = threadIdx.x;
    if (bx < 2) {
        const float* Q  = (bx == 0) ? muQ  : sigQ;
        const float* W  = (bx == 0) ? mu_w : sig_w;
        const float* bb = (bx == 0) ? mu_b : sig_b;
        for (int i = tid; i < 3072; i += 256) {
            int a = y[b*6 + (i >> 9)];
            xin[i] = Q[a*D + (i & 511)];
        }
        __syncthreads();
        const int d0 = tid, d1 = tid + 256;
        float acc0 = bb[d0], acc1 = bb[d1];
        const float4* x4 = (const float4*)xin;
        for (int i4 = 0; i4 < 768; ++i4) {
            float4 xv = x4[i4];
            int r = i4 * 4;
            acc0 += xv.x*W[(size_t)(r+0)*D+d0] + xv.y*W[(size_t)(r+1)*D+d0]
                  + xv.z*W[(size_t)(r+2)*D+d0] + xv.w*W[(size_t)(r+3)*D+d0];
            acc1 += xv.x*W[(size_t)(r+0)*D+d1] + xv.y*W[(size_t)(r+1)*D+d1]
                  + xv.z*W[(size_t)(r+2)*D+d1] + xv.w*W[(size_t)(r+3)*D+d1];
        }
        size_t base = ((size_t)b*SEQ + bx) * D;
        z[base + d0] = acc0 + pe_val(bx, d0);
        z[base + d1] = acc1 + pe_val(bx, d1);
    } else {
        const int f0 = (bx - 2) * 4;
        for (int idx = tid; idx < 600; idx += 256) {
            int i = idx >> 2, ff = idx & 3;
            xin[idx] = x[((size_t)(b*150 + i))*1024 + f0 + ff];
        }
        __syncthreads();
        const float4* x4 = (const float4*)xin;
        for (int dd = 0; dd < 2; ++dd) {
            const int d = tid + dd*256;
            float a0, a1, a2, a3;
            a0 = a1 = a2 = a3 = skel_b[d];
            for (int i = 0; i < 150; ++i) {
                float4 xv = x4[i];
                float w = skel_w[(size_t)i*D + d];
                a0 += xv.x*w; a1 += xv.y*w; a2 += xv.z*w; a3 += xv.w*w;
            }
            float a[4] = {a0, a1, a2, a3};
            #pragma unroll
            for (int ff = 0; ff < 4; ++ff) {
                int s = f0 + ff + 2;
                z[((size_t)b*SEQ + s)*D + d] = a[ff] + pe_val(s, d);
            }
        }
    }
}

// ---------------- GEMM (M x 512) @ (512 x 512) ----------------
__device__ __forceinline__ float4 ld_guard(const float* A, int m, int kcol, int M) {
    if (m < M) return *(const float4*)&A[(size_t)m*D + kcol];
    return make_float4(0.f, 0.f, 0.f, 0.f);
}

template<int EPI>
__launch_bounds__(256, 2)
__global__ void gemm512(const float* __restrict__ A, const float* __restrict__ W,
                        const float* __restrict__ bias, const float* __restrict__ resid,
                        float* __restrict__ out, int M)
{
    __shared__ float As[16*132];
    __shared__ float Bs[16*132];
    const int tid = threadIdx.x;
    const int tx = tid & 15, ty = tid >> 4;
    const int m0 = blockIdx.y * 128, n0 = blockIdx.x * 128;
    const int ar = tid >> 2, ac = (tid & 3) * 4;
    const int bkr = tid >> 5, bqc = (tid & 31) * 4;

    float acc[8][8];
    #pragma unroll
    for (int i = 0; i < 8; ++i)
        #pragma unroll
        for (int j = 0; j < 8; ++j) acc[i][j] = 0.f;

    for (int kt = 0; kt < 32; ++kt) {
        const int kb = kt * 16;
        float4 a0 = ld_guard(A, m0 + ar,      kb + ac, M);
        float4 a1 = ld_guard(A, m0 + ar + 64, kb + ac, M);
        float4 b0 = *(const float4*)&W[(size_t)(kb + bkr    )*D + n0 + bqc];
        float4 b1 = *(const float4*)&W[(size_t)(kb + bkr + 8)*D + n0 + bqc];
        if (kt) __syncthreads();
        As[(ac+0)*132 + ar] = a0.x; As[(ac+1)*132 + ar] = a0.y;
        As[(ac+2)*132 + ar] = a0.z; As[(ac+3)*132 + ar] = a0.w;
        As[(ac+0)*132 + ar + 64] = a1.x; As[(ac+1)*132 + ar + 64] = a1.y;
        As[(ac+2)*132 + ar + 64] = a1.z; As[(ac+3)*132 + ar + 64] = a1.w;
        *(float4*)&Bs[bkr*132 + bqc] = b0;
        *(float4*)&Bs[(bkr+8)*132 + bqc] = b1;
        __syncthreads();
        #pragma unroll
        for (int k = 0; k < 16; ++k) {
            float4 alo = *(const float4*)&As[k*132 + ty*4];
            float4 ahi = *(const float4*)&As[k*132 + 64 + ty*4];
            float4 blo = *(const float4*)&Bs[k*132 + tx*4];
            float4 bhi = *(const float4*)&Bs[k*132 + 64 + tx*4];
            float av[8] = {alo.x, alo.y, alo.z, alo.w, ahi.x, ahi.y, ahi.z, ahi.w};
            float bv[8] = {blo.x, blo.y, blo.z, blo.w, bhi.x, bhi.y, bhi.z, bhi.w};
            #pragma unroll
            for (int i = 0; i < 8; ++i)
                #pragma unroll
                for (int j = 0; j < 8; ++j) acc[i][j] += av[i] * bv[j];
        }
    }

    float4 blo = *(const float4*)&bias[n0 + tx*4];
    float4 bhi = *(const float4*)&bias[n0 + 64 + tx*4];
    #pragma unroll
    for (int i = 0; i < 8; ++i) {
        int m = m0 + ((i >> 2) << 6) + ty*4 + (i & 3);
        if (m >= M) continue;
        float o0 = acc[i][0] + blo.x, o1 = acc[i][1] + blo.y;
        float o2 = acc[i][2] + blo.z, o3 = acc[i][3] + blo.w;
        float o4 = acc[i][4] + bhi.x, o5 = acc[i][5] + bhi.y;
        float o6 = acc[i][6] + bhi.z, o7 = acc[i][7] + bhi.w;
        if (EPI == 0) {
            int bb = m / SEQ;
            int ss = m - bb * SEQ;
            int nlo = n0 + tx*4, nhi = nlo + 64;
            float* plo = out + ((size_t)(bb*H + (nlo >> 6)))*((size_t)SEQ*DH) + (size_t)ss*DH + (nlo & 63);
            float* phi = out + ((size_t)(bb*H + (nhi >> 6)))*((size_t)SEQ*DH) + (size_t)ss*DH + (nhi & 63);
            *(float4*)plo = make_float4(o0, o1, o2, o3);
            *(float4*)phi = make_float4(o4, o5, o6, o7);
        } else {
            size_t off = (size_t)m*D + n0 + tx*4;
            float4 r0 = *(const float4*)&resid[off];
            float4 r1 = *(const float4*)&resid[off + 64];
            *(float4*)&out[off]      = make_float4(o0+r0.x, o1+r0.y, o2+r0.z, o3+r0.w);
            *(float4*)&out[off + 64] = make_float4(o4+r1.x, o5+r1.y, o6+r1.z, o7+r1.w);
        }
    }
}

// ---------------- clustered attention: 1 block (1024 thr) per (b,h) ----------------
// q row in 16 NAMED float4 registers (rounds 2/3: any indexable local array --
// float[64] or float4[16] -- was sent to scratch: VGPR_Count=64, 377MB scratch
// writes/dispatch. Named scalars cannot be scratched.)
#define Q16(M) M(0) M(1) M(2) M(3) M(4) M(5) M(6) M(7) M(8) M(9) M(10) M(11) M(12) M(13) M(14) M(15)

__launch_bounds__(1024)
__global__ void attn_kernel(const float* __restrict__ q, const float* __restrict__ kk,
                            const float* __restrict__ v, float* __restrict__ o)
{
    __shared__ float At[NC][SEQP];       // 41.3 KB; doubles as part[16][NC][DH]
    __shared__ float cent[NC][DH];       // centroids; later attn-out rows
    __shared__ float tailrow[2][DH];     // q rows 1024/1025, later k rows
    __shared__ float cnorm[NC];
    __shared__ int   cnt[NC];
    __shared__ unsigned char assign[1028];
    __shared__ float redA[16][NC];
    __shared__ float redB[16][NC];
    __shared__ float Mc[NC];
    __shared__ float Sinv[NC];

    const int tid = threadIdx.x;
    const int wv = tid >> 6, lane = tid & 63;
    const int bh = blockIdx.x;
    const int b = bh >> 3, h = bh & 7;
    const float* qh = q  + (size_t)bh * SEQ * DH;
    const float* kh = kk + (size_t)bh * SEQ * DH;
    const float* vh = v  + (size_t)bh * SEQ * DH;
    float* oh = o + (size_t)b * SEQ * D + h * DH;
    float* part = &At[0][0];             // [16][NC][DH] flat: (w*NC+c)*DH+d

    // init: centroids = q[:10]; tail q rows staged to LDS
    if (tid < NC*DH) ((float*)cent)[tid] = qh[tid];
    if (tid >= NC*DH && tid < NC*DH + 2*DH) ((float*)tailrow)[tid - NC*DH] = qh[1024*DH + (tid - NC*DH)];

    // own q row -> 16 named float4 registers
    const float4* g4 = (const float4*)(qh + (size_t)tid * DH);
#define LQ(i) float4 q##i = g4[i];
    Q16(LQ)
#undef LQ
    __syncthreads();

    // ---- kmeans: 10 update iters + final assignment ----
    for (int iter = 0; iter <= KITERS; ++iter) {
        if (tid < NC) {
            float sn = 0.f;
            #pragma unroll
            for (int i = 0; i < 16; ++i) {
                float4 cv = *(const float4*)&cent[tid][i*4];
                sn += cv.x*cv.x + cv.y*cv.y + cv.z*cv.z + cv.w*cv.w;
            }
            cnorm[tid] = sn;
            cnt[tid] = 0;
        }
        __syncthreads();

        // assignment (named-register q vs LDS-broadcast centroids)
        int a_reg;
        {
            int best = 0; float bd = 1e30f;
            #pragma unroll
            for (int c = 0; c < NC; ++c) {
                float acc = 0.f;
#define DQ(i) { float4 cv = *(const float4*)&cent[c][(i)*4]; \
                acc += q##i.x*cv.x + q##i.y*cv.y + q##i.z*cv.z + q##i.w*cv.w; }
                Q16(DQ)
#undef DQ
                float dd = cnorm[c] - 2.f*acc;
                if (dd < bd) { bd = dd; best = c; }
            }
            a_reg = best;
            assign[tid] = (unsigned char)best;
        }
        if (iter < KITERS) {
            #pragma unroll
            for (int c = 0; c < NC; ++c) {
                unsigned long long m = __ballot(a_reg == c);
                if (lane == 0 && m) atomicAdd(&cnt[c], __popcll(m));
            }
        }
        if (tid < 2) {          // tail positions 1024,1025
            int best = 0; float bd = 1e30f;
            #pragma unroll
            for (int c = 0; c < NC; ++c) {
                float acc = 0.f;
                #pragma unroll
                for (int i = 0; i < 64; ++i) acc += tailrow[tid][i]*cent[c][i];
                float dd = cnorm[c] - 2.f*acc;
                if (dd < bd) { bd = dd; best = c; }
            }
            assign[1024 + tid] = (unsigned char)best;
            if (iter < KITERS) atomicAdd(&cnt[best], 1);
        }
        __syncthreads();
        if (iter == KITERS) break;

        // centroid update: wave wv covers s in [wv*64, wv*64+64); coalesced q reads
        {
            float accq[NC];
            #pragma unroll
            for (int c = 0; c < NC; ++c) accq[c] = 0.f;
            const int s0 = wv * 64;
            #pragma unroll 4
            for (int i = 0; i < 64; ++i) {
                int s = s0 + i;
                float qv = qh[(size_t)s*DH + lane];
                int c = assign[s];
                #pragma unroll
                for (int cc = 0; cc < NC; ++cc) accq[cc] += (cc == c) ? qv : 0.f;
            }
            if (wv < 2) {
                int c = assign[1024 + wv];
                float qv = tailrow[wv][lane];
                #pragma unroll
                for (int cc = 0; cc < NC; ++cc) accq[cc] += (cc == c) ? qv : 0.f;
            }
            #pragma unroll
            for (int c = 0; c < NC; ++c) part[(wv*NC + c)*DH + lane] = accq[c];
        }
        __syncthreads();
        if (tid < NC*DH) {
            int c = tid >> 6;
            float s = 0.f;
            #pragma unroll
            for (int w = 0; w < 16; ++w) s += part[w*(NC*DH) + tid];
            ((float*)cent)[tid] = s / fmaxf((float)cnt[c], 1.f);
        }
        __syncthreads();
    }

    // ---- logits: reuse the named registers for k row; tailrow for k tails ----
    if (tid < 2*DH) ((float*)tailrow)[tid] = kh[1024*DH + tid];
    {
        const float4* k4 = (const float4*)(kh + (size_t)tid * DH);
#define LK(i) q##i = k4[i];
        Q16(LK)
#undef LK
    }
    __syncthreads();

    float lg[NC], lgt[NC];
    #pragma unroll
    for (int c = 0; c < NC; ++c) {
        float acc = 0.f;
#define DK(i) { float4 cv = *(const float4*)&cent[c][(i)*4]; \
                acc += q##i.x*cv.x + q##i.y*cv.y + q##i.z*cv.z + q##i.w*cv.w; }
        Q16(DK)
#undef DK
        lg[c] = 0.125f * acc;
    }
    if (tid < 2) {
        #pragma unroll
        for (int c = 0; c < NC; ++c) {
            float acc = 0.f;
            #pragma unroll
            for (int i = 0; i < 64; ++i) acc += tailrow[tid][i]*cent[c][i];
            lgt[c] = 0.125f * acc;
        }
    }

    // softmax per cluster row: wave reduce -> 16-way LDS reduce
    #pragma unroll
    for (int c = 0; c < NC; ++c) {
        float m = lg[c];
        if (tid < 2) m = fmaxf(m, lgt[c]);
        #pragma unroll
        for (int off = 32; off; off >>= 1) m = fmaxf(m, __shfl_xor(m, off, 64));
        if (lane == 0) redA[wv][c] = m;
    }
    __syncthreads();
    if (tid < NC) {
        float m = redA[0][tid];
        #pragma unroll
        for (int w = 1; w < 16; ++w) m = fmaxf(m, redA[w][tid]);
        Mc[tid] = m;
    }
    __syncthreads();
    #pragma unroll
    for (int c = 0; c < NC; ++c) lg[c] = expf(lg[c] - Mc[c]);
    if (tid < 2) {
        #pragma unroll
        for (int c = 0; c < NC; ++c) lgt[c] = expf(lgt[c] - Mc[c]);
    }
    #pragma unroll
    for (int c = 0; c < NC; ++c) {
        float s = lg[c] + ((tid < 2) ? lgt[c] : 0.f);
        #pragma unroll
        for (int off = 32; off; off >>= 1) s += __shfl_xor(s, off, 64);
        if (lane == 0) redB[wv][c] = s;
    }
    __syncthreads();
    if (tid < NC) {
        float s = 0.f;
        #pragma unroll
        for (int w = 0; w < 16; ++w) s += redB[w][tid];
        Sinv[tid] = 1.f / s;
    }
    __syncthreads();
    #pragma unroll
    for (int c = 0; c < NC; ++c) At[c][tid] = lg[c] * Sinv[c];
    if (tid < 2) {
        #pragma unroll
        for (int c = 0; c < NC; ++c) At[c][1024 + tid] = lgt[c] * Sinv[c];
    }
    __syncthreads();

    // ---- A @ v: transposed, coalesced v reads, wave partials ----
    {
        float accv[NC];
        #pragma unroll
        for (int c = 0; c < NC; ++c) accv[c] = 0.f;
        const int s0 = wv * 64;
        for (int i = 0; i < 64; i += 4) {
            float vv0 = vh[(size_t)(s0+i  )*DH + lane];
            float vv1 = vh[(size_t)(s0+i+1)*DH + lane];
            float vv2 = vh[(size_t)(s0+i+2)*DH + lane];
            float vv3 = vh[(size_t)(s0+i+3)*DH + lane];
            #pragma unroll
            for (int c = 0; c < NC; ++c) {
                float4 av = *(const float4*)&At[c][s0+i];
                accv[c] += av.x*vv0 + av.y*vv1 + av.z*vv2 + av.w*vv3;
            }
        }
        if (wv < 2) {
            int s = 1024 + wv;
            float vv = vh[(size_t)s*DH + lane];
            #pragma unroll
            for (int c = 0; c < NC; ++c) accv[c] += At[c][s] * vv;
        }
        __syncthreads();   // all At reads done before part (same memory) is written
        #pragma unroll
        for (int c = 0; c < NC; ++c) part[(wv*NC + c)*DH + lane] = accv[c];
    }
    __syncthreads();
    if (tid < NC*DH) {     // reduce into cent (reused as attn-out rows)
        float s = 0.f;
        #pragma unroll
        for (int w = 0; w < 16; ++w) s += part[w*(NC*DH) + tid];
        ((float*)cent)[tid] = s;
    }
    __syncthreads();

    // ---- gather rows to output (coalesced 256B stores) ----
    {
        const int s0 = wv * 64;
        for (int i = 0; i < 64; ++i) {
            int s = s0 + i;
            oh[(size_t)s*D + lane] = cent[assign[s]][lane];
        }
        if (wv < 2) {
            int s = 1024 + wv;
            oh[(size_t)s*D + lane] = cent[assign[s]][lane];
        }
    }
}

// ---------------- fused LN1 + FFN + residual + LN2, one block per row ----------------
__launch_bounds__(256)
__global__ void ffn_ln_kernel(const float* __restrict__ in, float* __restrict__ z,
    const float* __restrict__ g1, const float* __restrict__ c1,
    const float* __restrict__ W1, const float* __restrict__ b1,
    const float* __restrict__ W2, const float* __restrict__ b2,
    const float* __restrict__ g2, const float* __restrict__ c2)
{
    __shared__ float red[8];
    __shared__ float redh[4][DFF];
    const int row = blockIdx.x, tid = threadIdx.x;
    const int lane = tid & 63, wid = tid >> 6;
    const float* r = in + (size_t)row * D;
    float x0 = r[tid], x1 = r[tid + 256];
    float s = x0 + x1, ss = x0*x0 + x1*x1;
    #pragma unroll
    for (int off = 32; off; off >>= 1) {
        s  += __shfl_xor(s,  off, 64);
        ss += __shfl_xor(ss, off, 64);
    }
    if (lane == 0) { red[wid] = s; red[4 + wid] = ss; }
    __syncthreads();
    float tot  = red[0] + red[1] + red[2] + red[3];
    float tot2 = red[4] + red[5] + red[6] + red[7];
    float mean = tot * (1.f/512.f);
    float var  = tot2 * (1.f/512.f) - mean*mean;
    float rstd = rsqrtf(var + 1e-5f);
    float za = (x0 - mean)*rstd*g1[tid]       + c1[tid];
    float zb = (x1 - mean)*rstd*g1[tid + 256] + c1[tid + 256];

    float p[DFF];
    #pragma unroll
    for (int j = 0; j < DFF; ++j)
        p[j] = za * W1[(size_t)tid*DFF + j] + zb * W1[(size_t)(tid+256)*DFF + j];
    #pragma unroll
    for (int off = 32; off; off >>= 1)
        #pragma unroll
        for (int j = 0; j < DFF; ++j) p[j] += __shfl_xor(p[j], off, 64);
    if (lane == 0) {
        #pragma unroll
        for (int j = 0; j < DFF; ++j) redh[wid][j] = p[j];
    }
    __syncthreads();
    float hv[DFF];
    #pragma unroll
    for (int j = 0; j < DFF; ++j)
        hv[j] = fmaxf(redh[0][j] + redh[1][j] + redh[2][j] + redh[3][j] + b1[j], 0.f);
    float y0 = b2[tid], y1 = b2[tid + 256];
    #pragma unroll
    for (int j = 0; j < DFF; ++j) {
        y0 += hv[j] * W2[(size_t)j*D + tid];
        y1 += hv[j] * W2[(size_t)j*D + tid + 256];
    }
    float t0 = za + y0, t1 = zb + y1;
    float s2 = t0 + t1, ss2 = t0*t0 + t1*t1;
    #pragma unroll
    for (int off = 32; off; off >>= 1) {
        s2  += __shfl_xor(s2,  off, 64);
        ss2 += __shfl_xor(ss2, off, 64);
    }
    if (lane == 0) { red[wid] = s2; red[4 + wid] = ss2; }
    __syncthreads();
    float tt  = red[0] + red[1] + red[2] + red[3];
    float tt2 = red[4] + red[5] + red[6] + red[7];
    float m2 = tt * (1.f/512.f);
    float v2 = tt2 * (1.f/512.f) - m2*m2;
    float rstd2 = rsqrtf(v2 + 1e-5f);
    float* zo = z + (size_t)row * D;
    zo[tid]       = (t0 - m2)*rstd2*g2[tid]       + c2[tid];
    zo[tid + 256] = (t1 - m2)*rstd2*g2[tid + 256] + c2[tid + 256];
}

// ---------------- extract mu / logvar ----------------
__launch_bounds__(256)
__global__ void extract_kernel(const float* __restrict__ z, float* __restrict__ out) {
    int i = blockIdx.x * 256 + threadIdx.x;
    if (i >= 2*BATCH*D) return;
    int half = i >> 13;
    int j = i & 8191;
    int b = j >> 9, d = j & 511;
    out[i] = z[((size_t)b*SEQ + half)*D + d];
}

extern "C" void kernel_launch(void* const* d_in, const int* in_sizes, int n_in,
                              void* d_out, int out_size, void* d_ws, size_t ws_size,
                              hipStream_t stream)
{
    const float* x      = (const float*)d_in[0];
    const int*   y      = (const int*)  d_in[1];
    const float* muQ    = (const float*)d_in[3];
    const float* sigQ   = (const float*)d_in[4];
    const float* mu_w   = (const float*)d_in[5];
    const float* mu_b   = (const float*)d_in[6];
    const float* sig_w  = (const float*)d_in[7];
    const float* sig_b  = (const float*)d_in[8];
    const float* skel_w = (const float*)d_in[9];
    const float* skel_b = (const float*)d_in[10];
    const float* Wq     = (const float*)d_in[11];
    const float* bq     = (const float*)d_in[12];
    const float* Wk     = (const float*)d_in[13];
    const float* bk     = (const float*)d_in[14];
    const float* Wv     = (const float*)d_in[15];
    const float* bv     = (const float*)d_in[16];
    const float* Wo     = (const float*)d_in[17];
    const float* bo     = (const float*)d_in[18];
    const float* g1     = (const float*)d_in[19];
    const float* c1     = (const float*)d_in[20];
    const float* g2     = (const float*)d_in[21];
    const float* c2     = (const float*)d_in[22];
    const float* W1     = (const float*)d_in[23];
    const float* b1     = (const float*)d_in[24];
    const float* W2     = (const float*)d_in[25];
    const float* b2     = (const float*)d_in[26];

    float* z  = (float*)d_ws;
    float* ob = z  + NBUF;   // attention output (B,S,D); also o-proj input
    float* qb = ob + NBUF;   // q (B*H,S,DH); reused as o-proj output
    float* kb = qb + NBUF;
    float* vb = kb + NBUF;

    embed_kernel<<<dim3(258, BATCH), 256, 0, stream>>>(
        x, y, muQ, sigQ, mu_w, mu_b, sig_w, sig_b, skel_w, skel_b, z);

    dim3 ggrid(4, 129);
    for (int l = 0; l < NLAYERS; ++l) {
        gemm512<0><<<ggrid, 256, 0, stream>>>(z, Wq + (size_t)l*D*D, bq + l*D, nullptr, qb, MR);
        gemm512<0><<<ggrid, 256, 0, stream>>>(z, Wk + (size_t)l*D*D, bk + l*D, nullptr, kb, MR);
        gemm512<0><<<ggrid, 256, 0, stream>>>(z, Wv + (size_t)l*D*D, bv + l*D, nullptr, vb, MR);
        attn_kernel<<<BATCH*H, 1024, 0, stream>>>(qb, kb, vb, ob);
        gemm512<1><<<ggrid, 256, 0, stream>>>(ob, Wo + (size_t)l*D*D, bo + l*D, z, qb, MR);
        ffn_ln_kernel<<<MR, 256, 0, stream>>>(qb, z,
            g1 + (size_t)l*D, c1 + (size_t)l*D,
            W1 + (size_t)l*D*DFF, b1 + (size_t)l*DFF,
            W2 + (size_t)l*DFF*D, b2 + (size_t)l*D,
            g2 + (size_t)l*D, c2 + (size_t)l*D);
    }
    extract_kernel<<<64, 256, 0, stream>>>(z, (float*)d_out);

    (void)in_sizes; (void)n_in; (void)out_size; (void)ws_size;
}

// Round 5
// 7610.339 us; speedup vs baseline: 1.5263x; 1.2616x over previous
//
#include <hip/hip_runtime.h>
#include <math.h>

#define D 512
#define H 8
#define DH 64
#define NLAYERS 8
#define DFF 8
#define NC 10
#define KITERS 10
#define SEQ 1026
#define SEQP 1032
#define BATCH 16
#define MR (BATCH*SEQ)            // 16416 rows
#define NBUF ((size_t)MR * D)     // floats per big buffer

__device__ __forceinline__ float pe_val(int s, int d) {
    float e = (float)(d & ~1);
    float dv = expf(e * (-9.210340371976184f / 512.0f));   // ln(10000)/512
    float ph = (float)s * dv;
    return (d & 1) ? cosf(ph) : sinf(ph);
}

// ---------------- embed ----------------
__launch_bounds__(256)
__global__ void embed_kernel(const float* __restrict__ x, const int* __restrict__ y,
    const float* __restrict__ muQ, const float* __restrict__ sigQ,
    const float* __restrict__ mu_w, const float* __restrict__ mu_b,
    const float* __restrict__ sig_w, const float* __restrict__ sig_b,
    const float* __restrict__ skel_w, const float* __restrict__ skel_b,
    float* __restrict__ z)
{
    __shared__ float xin[3072];
    const int bx = blockIdx.x, b = blockIdx.y, tid = threadIdx.x;
    if (bx < 2) {
        const float* Q  = (bx == 0) ? muQ  : sigQ;
        const float* W  = (bx == 0) ? mu_w : sig_w;
        const float* bb = (bx == 0) ? mu_b : sig_b;
        for (int i = tid; i < 3072; i += 256) {
            int a = y[b*6 + (i >> 9)];
            xin[i] = Q[a*D + (i & 511)];
        }
        __syncthreads();
        const int d0 = tid, d1 = tid + 256;
        float acc0 = bb[d0], acc1 = bb[d1];
        const float4* x4 = (const float4*)xin;
        for (int i4 = 0; i4 < 768; ++i4) {
            float4 xv = x4[i4];
            int r = i4 * 4;
            acc0 += xv.x*W[(size_t)(r+0)*D+d0] + xv.y*W[(size_t)(r+1)*D+d0]
                  + xv.z*W[(size_t)(r+2)*D+d0] + xv.w*W[(size_t)(r+3)*D+d0];
            acc1 += xv.x*W[(size_t)(r+0)*D+d1] + xv.y*W[(size_t)(r+1)*D+d1]
                  + xv.z*W[(size_t)(r+2)*D+d1] + xv.w*W[(size_t)(r+3)*D+d1];
        }
        size_t base = ((size_t)b*SEQ + bx) * D;
        z[base + d0] = acc0 + pe_val(bx, d0);
        z[base + d1] = acc1 + pe_val(bx, d1);
    } else {
        const int f0 = (bx - 2) * 4;
        for (int idx = tid; idx < 600; idx += 256) {
            int i = idx >> 2, ff = idx & 3;
            xin[idx] = x[((size_t)(b*150 + i))*1024 + f0 + ff];
        }
        __syncthreads();
        const float4* x4 = (const float4*)xin;
        for (int dd = 0; dd < 2; ++dd) {
            const int d = tid + dd*256;
            float a0, a1, a2, a3;
            a0 = a1 = a2 = a3 = skel_b[d];
            for (int i = 0; i < 150; ++i) {
                float4 xv = x4[i];
                float w = skel_w[(size_t)i*D + d];
                a0 += xv.x*w; a1 += xv.y*w; a2 += xv.z*w; a3 += xv.w*w;
            }
            float a[4] = {a0, a1, a2, a3};
            #pragma unroll
            for (int ff = 0; ff < 4; ++ff) {
                int s = f0 + ff + 2;
                z[((size_t)b*SEQ + s)*D + d] = a[ff] + pe_val(s, d);
            }
        }
    }
}

// ---------------- GEMM (M x 512) @ (512 x 512) ----------------
__device__ __forceinline__ float4 ld_guard(const float* A, int m, int kcol, int M) {
    if (m < M) return *(const float4*)&A[(size_t)m*D + kcol];
    return make_float4(0.f, 0.f, 0.f, 0.f);
}

template<int EPI>
__launch_bounds__(256, 2)
__global__ void gemm512(const float* __restrict__ A, const float* __restrict__ W,
                        const float* __restrict__ bias, const float* __restrict__ resid,
                        float* __restrict__ out, int M)
{
    __shared__ float As[16*132];
    __shared__ float Bs[16*132];
    const int tid = threadIdx.x;
    const int tx = tid & 15, ty = tid >> 4;
    const int m0 = blockIdx.y * 128, n0 = blockIdx.x * 128;
    const int ar = tid >> 2, ac = (tid & 3) * 4;
    const int bkr = tid >> 5, bqc = (tid & 31) * 4;

    float acc[8][8];
    #pragma unroll
    for (int i = 0; i < 8; ++i)
        #pragma unroll
        for (int j = 0; j < 8; ++j) acc[i][j] = 0.f;

    for (int kt = 0; kt < 32; ++kt) {
        const int kb = kt * 16;
        float4 a0 = ld_guard(A, m0 + ar,      kb + ac, M);
        float4 a1 = ld_guard(A, m0 + ar + 64, kb + ac, M);
        float4 b0 = *(const float4*)&W[(size_t)(kb + bkr    )*D + n0 + bqc];
        float4 b1 = *(const float4*)&W[(size_t)(kb + bkr + 8)*D + n0 + bqc];
        if (kt) __syncthreads();
        As[(ac+0)*132 + ar] = a0.x; As[(ac+1)*132 + ar] = a0.y;
        As[(ac+2)*132 + ar] = a0.z; As[(ac+3)*132 + ar] = a0.w;
        As[(ac+0)*132 + ar + 64] = a1.x; As[(ac+1)*132 + ar + 64] = a1.y;
        As[(ac+2)*132 + ar + 64] = a1.z; As[(ac+3)*132 + ar + 64] = a1.w;
        *(float4*)&Bs[bkr*132 + bqc] = b0;
        *(float4*)&Bs[(bkr+8)*132 + bqc] = b1;
        __syncthreads();
        #pragma unroll
        for (int k = 0; k < 16; ++k) {
            float4 alo = *(const float4*)&As[k*132 + ty*4];
            float4 ahi = *(const float4*)&As[k*132 + 64 + ty*4];
            float4 blo = *(const float4*)&Bs[k*132 + tx*4];
            float4 bhi = *(const float4*)&Bs[k*132 + 64 + tx*4];
            float av[8] = {alo.x, alo.y, alo.z, alo.w, ahi.x, ahi.y, ahi.z, ahi.w};
            float bv[8] = {blo.x, blo.y, blo.z, blo.w, bhi.x, bhi.y, bhi.z, bhi.w};
            #pragma unroll
            for (int i = 0; i < 8; ++i)
                #pragma unroll
                for (int j = 0; j < 8; ++j) acc[i][j] += av[i] * bv[j];
        }
    }

    float4 blo = *(const float4*)&bias[n0 + tx*4];
    float4 bhi = *(const float4*)&bias[n0 + 64 + tx*4];
    #pragma unroll
    for (int i = 0; i < 8; ++i) {
        int m = m0 + ((i >> 2) << 6) + ty*4 + (i & 3);
        if (m >= M) continue;
        float o0 = acc[i][0] + blo.x, o1 = acc[i][1] + blo.y;
        float o2 = acc[i][2] + blo.z, o3 = acc[i][3] + blo.w;
        float o4 = acc[i][4] + bhi.x, o5 = acc[i][5] + bhi.y;
        float o6 = acc[i][6] + bhi.z, o7 = acc[i][7] + bhi.w;
        if (EPI == 0) {
            int bb = m / SEQ;
            int ss = m - bb * SEQ;
            int nlo = n0 + tx*4, nhi = nlo + 64;
            float* plo = out + ((size_t)(bb*H + (nlo >> 6)))*((size_t)SEQ*DH) + (size_t)ss*DH + (nlo & 63);
            float* phi = out + ((size_t)(bb*H + (nhi >> 6)))*((size_t)SEQ*DH) + (size_t)ss*DH + (nhi & 63);
            *(float4*)plo = make_float4(o0, o1, o2, o3);
            *(float4*)phi = make_float4(o4, o5, o6, o7);
        } else {
            size_t off = (size_t)m*D + n0 + tx*4;
            float4 r0 = *(const float4*)&resid[off];
            float4 r1 = *(const float4*)&resid[off + 64];
            *(float4*)&out[off]      = make_float4(o0+r0.x, o1+r0.y, o2+r0.z, o3+r0.w);
            *(float4*)&out[off + 64] = make_float4(o4+r1.x, o5+r1.y, o6+r1.z, o7+r1.w);
        }
    }
}

// ---------------- clustered attention: 1 block (1024 thr) per (b,h) ----------------
// NO per-thread q persistence (rounds 2-4: any 64-float/thread design spilled to
// scratch -- 375MB/dispatch). q/k rows are re-read from global each pass; the
// per-block 262KB slice is L2-resident (round-1 evidence: FETCH=103MB with 21
// full re-read passes). Peak live registers ~40.
__launch_bounds__(1024, 4)
__global__ void attn_kernel(const float* __restrict__ q, const float* __restrict__ kk,
                            const float* __restrict__ v, float* __restrict__ o)
{
    __shared__ float At[NC][SEQP];       // 41.3 KB; doubles as part[16][NC][DH]
    __shared__ float cent[NC][DH];       // centroids; later attn-out rows
    __shared__ float tailrow[2][DH];     // q rows 1024/1025, later k rows
    __shared__ float cnorm[NC];
    __shared__ int   cnt[NC];
    __shared__ unsigned char assign[1028];
    __shared__ float redA[16][NC];
    __shared__ float redB[16][NC];
    __shared__ float Mc[NC];
    __shared__ float Sinv[NC];

    const int tid = threadIdx.x;
    const int wv = tid >> 6, lane = tid & 63;
    const int bh = blockIdx.x;
    const int b = bh >> 3, h = bh & 7;
    const float* qh = q  + (size_t)bh * SEQ * DH;
    const float* kh = kk + (size_t)bh * SEQ * DH;
    const float* vh = v  + (size_t)bh * SEQ * DH;
    float* oh = o + (size_t)b * SEQ * D + h * DH;
    float* part = &At[0][0];             // [16][NC][DH] flat: (w*NC+c)*DH+d

    // init: centroids = q[:10]; tail q rows staged to LDS
    if (tid < NC*DH) ((float*)cent)[tid] = qh[tid];
    if (tid >= NC*DH && tid < NC*DH + 2*DH) ((float*)tailrow)[tid - NC*DH] = qh[1024*DH + (tid - NC*DH)];
    __syncthreads();

    const float4* qrow4 = (const float4*)(qh + (size_t)tid * DH);

    // ---- kmeans: 10 update iters + final assignment ----
    for (int iter = 0; iter <= KITERS; ++iter) {
        if (tid < NC) {
            float sn = 0.f;
            #pragma unroll
            for (int i = 0; i < 16; ++i) {
                float4 cv = *(const float4*)&cent[tid][i*4];
                sn += cv.x*cv.x + cv.y*cv.y + cv.z*cv.z + cv.w*cv.w;
            }
            cnorm[tid] = sn;
            cnt[tid] = 0;
        }
        __syncthreads();

        // assignment: one position per thread; q row streamed float4-at-a-time
        int a_reg;
        {
            float acc[NC];
            #pragma unroll
            for (int c = 0; c < NC; ++c) acc[c] = 0.f;
            #pragma unroll 4
            for (int kq = 0; kq < 16; ++kq) {
                float4 qv = qrow4[kq];
                #pragma unroll
                for (int c = 0; c < NC; ++c) {
                    float4 cv = *(const float4*)&cent[c][kq*4];
                    acc[c] += qv.x*cv.x + qv.y*cv.y + qv.z*cv.z + qv.w*cv.w;
                }
            }
            int best = 0; float bd = 1e30f;
            #pragma unroll
            for (int c = 0; c < NC; ++c) {
                float dd = cnorm[c] - 2.f*acc[c];
                if (dd < bd) { bd = dd; best = c; }
            }
            a_reg = best;
            assign[tid] = (unsigned char)best;
        }
        if (iter < KITERS) {
            #pragma unroll
            for (int c = 0; c < NC; ++c) {
                unsigned long long m = __ballot(a_reg == c);
                if (lane == 0 && m) atomicAdd(&cnt[c], __popcll(m));
            }
        }
        if (tid < 2) {          // tail positions 1024,1025
            int best = 0; float bd = 1e30f;
            #pragma unroll
            for (int c = 0; c < NC; ++c) {
                float acc = 0.f;
                #pragma unroll
                for (int i = 0; i < 64; ++i) acc += tailrow[tid][i]*cent[c][i];
                float dd = cnorm[c] - 2.f*acc;
                if (dd < bd) { bd = dd; best = c; }
            }
            assign[1024 + tid] = (unsigned char)best;
            if (iter < KITERS) atomicAdd(&cnt[best], 1);
        }
        __syncthreads();
        if (iter == KITERS) break;

        // centroid update: wave wv covers s in [wv*64, wv*64+64); coalesced q reads (L2-hot)
        {
            float accq[NC];
            #pragma unroll
            for (int c = 0; c < NC; ++c) accq[c] = 0.f;
            const int s0 = wv * 64;
            #pragma unroll 4
            for (int i = 0; i < 64; ++i) {
                int s = s0 + i;
                float qv = qh[(size_t)s*DH + lane];
                int c = assign[s];
                #pragma unroll
                for (int cc = 0; cc < NC; ++cc) accq[cc] += (cc == c) ? qv : 0.f;
            }
            if (wv < 2) {
                int c = assign[1024 + wv];
                float qv = tailrow[wv][lane];
                #pragma unroll
                for (int cc = 0; cc < NC; ++cc) accq[cc] += (cc == c) ? qv : 0.f;
            }
            #pragma unroll
            for (int c = 0; c < NC; ++c) part[(wv*NC + c)*DH + lane] = accq[c];
        }
        __syncthreads();
        if (tid < NC*DH) {
            int c = tid >> 6;
            float s = 0.f;
            #pragma unroll
            for (int w = 0; w < 16; ++w) s += part[w*(NC*DH) + tid];
            ((float*)cent)[tid] = s / fmaxf((float)cnt[c], 1.f);
        }
        __syncthreads();
    }

    // ---- logits: k row streamed from global; tailrow re-staged with k tails ----
    if (tid < 2*DH) ((float*)tailrow)[tid] = kh[1024*DH + tid];
    __syncthreads();

    float lg[NC], lgt[NC];
    {
        const float4* krow4 = (const float4*)(kh + (size_t)tid * DH);
        #pragma unroll
        for (int c = 0; c < NC; ++c) lg[c] = 0.f;
        #pragma unroll 4
        for (int kq = 0; kq < 16; ++kq) {
            float4 kv = krow4[kq];
            #pragma unroll
            for (int c = 0; c < NC; ++c) {
                float4 cv = *(const float4*)&cent[c][kq*4];
                lg[c] += kv.x*cv.x + kv.y*cv.y + kv.z*cv.z + kv.w*cv.w;
            }
        }
        #pragma unroll
        for (int c = 0; c < NC; ++c) lg[c] *= 0.125f;
    }
    if (tid < 2) {
        #pragma unroll
        for (int c = 0; c < NC; ++c) {
            float acc = 0.f;
            #pragma unroll
            for (int i = 0; i < 64; ++i) acc += tailrow[tid][i]*cent[c][i];
            lgt[c] = 0.125f * acc;
        }
    }

    // softmax per cluster row: wave reduce -> 16-way LDS reduce
    #pragma unroll
    for (int c = 0; c < NC; ++c) {
        float m = lg[c];
        if (tid < 2) m = fmaxf(m, lgt[c]);
        #pragma unroll
        for (int off = 32; off; off >>= 1) m = fmaxf(m, __shfl_xor(m, off, 64));
        if (lane == 0) redA[wv][c] = m;
    }
    __syncthreads();
    if (tid < NC) {
        float m = redA[0][tid];
        #pragma unroll
        for (int w = 1; w < 16; ++w) m = fmaxf(m, redA[w][tid]);
        Mc[tid] = m;
    }
    __syncthreads();
    #pragma unroll
    for (int c = 0; c < NC; ++c) lg[c] = expf(lg[c] - Mc[c]);
    if (tid < 2) {
        #pragma unroll
        for (int c = 0; c < NC; ++c) lgt[c] = expf(lgt[c] - Mc[c]);
    }
    #pragma unroll
    for (int c = 0; c < NC; ++c) {
        float s = lg[c] + ((tid < 2) ? lgt[c] : 0.f);
        #pragma unroll
        for (int off = 32; off; off >>= 1) s += __shfl_xor(s, off, 64);
        if (lane == 0) redB[wv][c] = s;
    }
    __syncthreads();
    if (tid < NC) {
        float s = 0.f;
        #pragma unroll
        for (int w = 0; w < 16; ++w) s += redB[w][tid];
        Sinv[tid] = 1.f / s;
    }
    __syncthreads();
    #pragma unroll
    for (int c = 0; c < NC; ++c) At[c][tid] = lg[c] * Sinv[c];
    if (tid < 2) {
        #pragma unroll
        for (int c = 0; c < NC; ++c) At[c][1024 + tid] = lgt[c] * Sinv[c];
    }
    __syncthreads();

    // ---- A @ v: transposed, coalesced v reads, wave partials ----
    {
        float accv[NC];
        #pragma unroll
        for (int c = 0; c < NC; ++c) accv[c] = 0.f;
        const int s0 = wv * 64;
        for (int i = 0; i < 64; i += 4) {
            float vv0 = vh[(size_t)(s0+i  )*DH + lane];
            float vv1 = vh[(size_t)(s0+i+1)*DH + lane];
            float vv2 = vh[(size_t)(s0+i+2)*DH + lane];
            float vv3 = vh[(size_t)(s0+i+3)*DH + lane];
            #pragma unroll
            for (int c = 0; c < NC; ++c) {
                float4 av = *(const float4*)&At[c][s0+i];
                accv[c] += av.x*vv0 + av.y*vv1 + av.z*vv2 + av.w*vv3;
            }
        }
        if (wv < 2) {
            int s = 1024 + wv;
            float vv = vh[(size_t)s*DH + lane];
            #pragma unroll
            for (int c = 0; c < NC; ++c) accv[c] += At[c][s] * vv;
        }
        __syncthreads();   // all At reads done before part (same memory) is written
        #pragma unroll
        for (int c = 0; c < NC; ++c) part[(wv*NC + c)*DH + lane] = accv[c];
    }
    __syncthreads();
    if (tid < NC*DH) {     // reduce into cent (reused as attn-out rows)
        float s = 0.f;
        #pragma unroll
        for (int w = 0; w < 16; ++w) s += part[w*(NC*DH) + tid];
        ((float*)cent)[tid] = s;
    }
    __syncthreads();

    // ---- gather rows to output (coalesced 256B stores) ----
    {
        const int s0 = wv * 64;
        #pragma unroll 4
        for (int i = 0; i < 64; ++i) {
            int s = s0 + i;
            oh[(size_t)s*D + lane] = cent[assign[s]][lane];
        }
        if (wv < 2) {
            int s = 1024 + wv;
            oh[(size_t)s*D + lane] = cent[assign[s]][lane];
        }
    }
}

// ---------------- fused LN1 + FFN + residual + LN2, one block per row ----------------
__launch_bounds__(256)
__global__ void ffn_ln_kernel(const float* __restrict__ in, float* __restrict__ z,
    const float* __restrict__ g1, const float* __restrict__ c1,
    const float* __restrict__ W1, const float* __restrict__ b1,
    const float* __restrict__ W2, const float* __restrict__ b2,
    const float* __restrict__ g2, const float* __restrict__ c2)
{
    __shared__ float red[8];
    __shared__ float redh[4][DFF];
    const int row = blockIdx.x, tid = threadIdx.x;
    const int lane = tid & 63, wid = tid >> 6;
    const float* r = in + (size_t)row * D;
    float x0 = r[tid], x1 = r[tid + 256];
    float s = x0 + x1, ss = x0*x0 + x1*x1;
    #pragma unroll
    for (int off = 32; off; off >>= 1) {
        s  += __shfl_xor(s,  off, 64);
        ss += __shfl_xor(ss, off, 64);
    }
    if (lane == 0) { red[wid] = s; red[4 + wid] = ss; }
    __syncthreads();
    float tot  = red[0] + red[1] + red[2] + red[3];
    float tot2 = red[4] + red[5] + red[6] + red[7];
    float mean = tot * (1.f/512.f);
    float var  = tot2 * (1.f/512.f) - mean*mean;
    float rstd = rsqrtf(var + 1e-5f);
    float za = (x0 - mean)*rstd*g1[tid]       + c1[tid];
    float zb = (x1 - mean)*rstd*g1[tid + 256] + c1[tid + 256];

    float p[DFF];
    #pragma unroll
    for (int j = 0; j < DFF; ++j)
        p[j] = za * W1[(size_t)tid*DFF + j] + zb * W1[(size_t)(tid+256)*DFF + j];
    #pragma unroll
    for (int off = 32; off; off >>= 1)
        #pragma unroll
        for (int j = 0; j < DFF; ++j) p[j] += __shfl_xor(p[j], off, 64);
    if (lane == 0) {
        #pragma unroll
        for (int j = 0; j < DFF; ++j) redh[wid][j] = p[j];
    }
    __syncthreads();
    float hv[DFF];
    #pragma unroll
    for (int j = 0; j < DFF; ++j)
        hv[j] = fmaxf(redh[0][j] + redh[1][j] + redh[2][j] + redh[3][j] + b1[j], 0.f);
    float y0 = b2[tid], y1 = b2[tid + 256];
    #pragma unroll
    for (int j = 0; j < DFF; ++j) {
        y0 += hv[j] * W2[(size_t)j*D + tid];
        y1 += hv[j] * W2[(size_t)j*D + tid + 256];
    }
    float t0 = za + y0, t1 = zb + y1;
    float s2 = t0 + t1, ss2 = t0*t0 + t1*t1;
    #pragma unroll
    for (int off = 32; off; off >>= 1) {
        s2  += __shfl_xor(s2,  off, 64);
        ss2 += __shfl_xor(ss2, off, 64);
    }
    if (lane == 0) { red[wid] = s2; red[4 + wid] = ss2; }
    __syncthreads();
    float tt  = red[0] + red[1] + red[2] + red[3];
    float tt2 = red[4] + red[5] + red[6] + red[7];
    float m2 = tt * (1.f/512.f);
    float v2 = tt2 * (1.f/512.f) - m2*m2;
    float rstd2 = rsqrtf(v2 + 1e-5f);
    float* zo = z + (size_t)row * D;
    zo[tid]       = (t0 - m2)*rstd2*g2[tid]       + c2[tid];
    zo[tid + 256] = (t1 - m2)*rstd2*g2[tid + 256] + c2[tid + 256];
}

// ---------------- extract mu / logvar ----------------
__launch_bounds__(256)
__global__ void extract_kernel(const float* __restrict__ z, float* __restrict__ out) {
    int i = blockIdx.x * 256 + threadIdx.x;
    if (i >= 2*BATCH*D) return;
    int half = i >> 13;
    int j = i & 8191;
    int b = j >> 9, d = j & 511;
    out[i] = z[((size_t)b*SEQ + half)*D + d];
}

extern "C" void kernel_launch(void* const* d_in, const int* in_sizes, int n_in,
                              void* d_out, int out_size, void* d_ws, size_t ws_size,
                              hipStream_t stream)
{
    const float* x      = (const float*)d_in[0];
    const int*   y      = (const int*)  d_in[1];
    const float* muQ    = (const float*)d_in[3];
    const float* sigQ   = (const float*)d_in[4];
    const float* mu_w   = (const float*)d_in[5];
    const float* mu_b   = (const float*)d_in[6];
    const float* sig_w  = (const float*)d_in[7];
    const float* sig_b  = (const float*)d_in[8];
    const float* skel_w = (const float*)d_in[9];
    const float* skel_b = (const float*)d_in[10];
    const float* Wq     = (const float*)d_in[11];
    const float* bq     = (const float*)d_in[12];
    const float* Wk     = (const float*)d_in[13];
    const float* bk     = (const float*)d_in[14];
    const float* Wv     = (const float*)d_in[15];
    const float* bv     = (const float*)d_in[16];
    const float* Wo     = (const float*)d_in[17];
    const float* bo     = (const float*)d_in[18];
    const float* g1     = (const float*)d_in[19];
    const float* c1     = (const float*)d_in[20];
    const float* g2     = (const float*)d_in[21];
    const float* c2     = (const float*)d_in[22];
    const float* W1     = (const float*)d_in[23];
    const float* b1     = (const float*)d_in[24];
    const float* W2     = (const float*)d_in[25];
    const float* b2     = (const float*)d_in[26];

    float* z  = (float*)d_ws;
    float* ob = z  + NBUF;   // attention output (B,S,D); also o-proj input
    float* qb = ob + NBUF;   // q (B*H,S,DH); reused as o-proj output
    float* kb = qb + NBUF;
    float* vb = kb + NBUF;

    embed_kernel<<<dim3(258, BATCH), 256, 0, stream>>>(
        x, y, muQ, sigQ, mu_w, mu_b, sig_w, sig_b, skel_w, skel_b, z);

    dim3 ggrid(4, 129);
    for (int l = 0; l < NLAYERS; ++l) {
        gemm512<0><<<ggrid, 256, 0, stream>>>(z, Wq + (size_t)l*D*D, bq + l*D, nullptr, qb, MR);
        gemm512<0><<<ggrid, 256, 0, stream>>>(z, Wk + (size_t)l*D*D, bk + l*D, nullptr, kb, MR);
        gemm512<0><<<ggrid, 256, 0, stream>>>(z, Wv + (size_t)l*D*D, bv + l*D, nullptr, vb, MR);
        attn_kernel<<<BATCH*H, 1024, 0, stream>>>(qb, kb, vb, ob);
        gemm512<1><<<ggrid, 256, 0, stream>>>(ob, Wo + (size_t)l*D*D, bo + l*D, z, qb, MR);
        ffn_ln_kernel<<<MR, 256, 0, stream>>>(qb, z,
            g1 + (size_t)l*D, c1 + (size_t)l*D,
            W1 + (size_t)l*D*DFF, b1 + (size_t)l*DFF,
            W2 + (size_t)l*DFF*D, b2 + (size_t)l*D,
            g2 + (size_t)l*D, c2 + (size_t)l*D);
    }
    extract_kernel<<<64, 256, 0, stream>>>(z, (float*)d_out);

    (void)in_sizes; (void)n_in; (void)out_size; (void)ws_size;
}

// Round 7
// 4910.785 us; speedup vs baseline: 2.3654x; 1.5497x over previous
//
#include <hip/hip_runtime.h>
#include <hip/hip_fp16.h>
#include <math.h>

#define D 512
#define H 8
#define DH 64
#define NLAYERS 8
#define DFF 8
#define NC 10
#define KITERS 10
#define SEQ 1026
#define SEQP 1032
#define BATCH 16
#define MR (BATCH*SEQ)            // 16416 rows
#define NBUF ((size_t)MR * D)     // floats per big activation buffer
#define DD ((size_t)D * D)

typedef _Float16 f16;
typedef f16 f16x8 __attribute__((ext_vector_type(8)));
typedef float f32x4 __attribute__((ext_vector_type(4)));

__device__ __forceinline__ void split2(float x, float y, unsigned& uh, unsigned& ul) {
    __half hx = __float2half_rn(x), hy = __float2half_rn(y);
    __half lx = __float2half_rn(x - __half2float(hx));
    __half ly = __float2half_rn(y - __half2float(hy));
    uh = (unsigned)__half_as_ushort(hx) | ((unsigned)__half_as_ushort(hy) << 16);
    ul = (unsigned)__half_as_ushort(lx) | ((unsigned)__half_as_ushort(ly) << 16);
}

__device__ __forceinline__ float pe_val(int s, int d) {
    float e = (float)(d & ~1);
    float dv = expf(e * (-9.210340371976184f / 512.0f));   // ln(10000)/512
    float ph = (float)s * dv;
    return (d & 1) ? cosf(ph) : sinf(ph);
}

// ---------------- per-layer weight split+transpose: W[k][n] f32 -> WT[n][k] f16 hi/lo ----------------
// grid (8,8,4): z selects {Wq,Wk,Wv,Wo} of ONE layer; output [4][512][512]
__launch_bounds__(256)
__global__ void convert_w(const float* __restrict__ Wq, const float* __restrict__ Wk,
                          const float* __restrict__ Wv, const float* __restrict__ Wo,
                          ushort* __restrict__ whiT, ushort* __restrict__ wloT)
{
    __shared__ float tile[64][65];
    const int tid = threadIdx.x;
    const int k0 = blockIdx.x * 64, n0 = blockIdx.y * 64, m = blockIdx.z;
    const float* W;
    switch (m) { case 0: W = Wq; break; case 1: W = Wk; break;
                 case 2: W = Wv; break; default: W = Wo; }
    {
        int r = tid >> 4, c = (tid & 15) * 4;
        #pragma unroll
        for (int p = 0; p < 4; ++p) {
            float4 v = *(const float4*)&W[(size_t)(k0 + r + p*16)*D + n0 + c];
            tile[r + p*16][c]   = v.x; tile[r + p*16][c+1] = v.y;
            tile[r + p*16][c+2] = v.z; tile[r + p*16][c+3] = v.w;
        }
    }
    __syncthreads();
    ushort* ohp = whiT + (size_t)m * DD;
    ushort* olp = wloT + (size_t)m * DD;
    {
        int nl = tid >> 3, kc = (tid & 7) * 8;
        #pragma unroll
        for (int p = 0; p < 2; ++p) {
            int n = nl + p*32;
            uint4 UH, UL;
            split2(tile[kc+0][n], tile[kc+1][n], UH.x, UL.x);
            split2(tile[kc+2][n], tile[kc+3][n], UH.y, UL.y);
            split2(tile[kc+4][n], tile[kc+5][n], UH.z, UL.z);
            split2(tile[kc+6][n], tile[kc+7][n], UH.w, UL.w);
            size_t off = (size_t)(n0 + n)*D + k0 + kc;
            *(uint4*)&ohp[off] = UH;
            *(uint4*)&olp[off] = UL;
        }
    }
}

// ---------------- embed ----------------
__launch_bounds__(256)
__global__ void embed_kernel(const float* __restrict__ x, const int* __restrict__ y,
    const float* __restrict__ muQ, const float* __restrict__ sigQ,
    const float* __restrict__ mu_w, const float* __restrict__ mu_b,
    const float* __restrict__ sig_w, const float* __restrict__ sig_b,
    const float* __restrict__ skel_w, const float* __restrict__ skel_b,
    float* __restrict__ z)
{
    __shared__ float xin[3072];
    const int bx = blockIdx.x, b = blockIdx.y, tid = threadIdx.x;
    if (bx < 2) {
        const float* Q  = (bx == 0) ? muQ  : sigQ;
        const float* W  = (bx == 0) ? mu_w : sig_w;
        const float* bb = (bx == 0) ? mu_b : sig_b;
        for (int i = tid; i < 3072; i += 256) {
            int a = y[b*6 + (i >> 9)];
            xin[i] = Q[a*D + (i & 511)];
        }
        __syncthreads();
        const int d0 = tid, d1 = tid + 256;
        float acc0 = bb[d0], acc1 = bb[d1];
        const float4* x4 = (const float4*)xin;
        for (int i4 = 0; i4 < 768; ++i4) {
            float4 xv = x4[i4];
            int r = i4 * 4;
            acc0 += xv.x*W[(size_t)(r+0)*D+d0] + xv.y*W[(size_t)(r+1)*D+d0]
                  + xv.z*W[(size_t)(r+2)*D+d0] + xv.w*W[(size_t)(r+3)*D+d0];
            acc1 += xv.x*W[(size_t)(r+0)*D+d1] + xv.y*W[(size_t)(r+1)*D+d1]
                  + xv.z*W[(size_t)(r+2)*D+d1] + xv.w*W[(size_t)(r+3)*D+d1];
        }
        size_t base = ((size_t)b*SEQ + bx) * D;
        z[base + d0] = acc0 + pe_val(bx, d0);
        z[base + d1] = acc1 + pe_val(bx, d1);
    } else {
        const int f0 = (bx - 2) * 4;
        for (int idx = tid; idx < 600; idx += 256) {
            int i = idx >> 2, ff = idx & 3;
            xin[idx] = x[((size_t)(b*150 + i))*1024 + f0 + ff];
        }
        __syncthreads();
        const float4* x4 = (const float4*)xin;
        for (int dd = 0; dd < 2; ++dd) {
            const int d = tid + dd*256;
            float a0, a1, a2, a3;
            a0 = a1 = a2 = a3 = skel_b[d];
            for (int i = 0; i < 150; ++i) {
                float4 xv = x4[i];
                float w = skel_w[(size_t)i*D + d];
                a0 += xv.x*w; a1 += xv.y*w; a2 += xv.z*w; a3 += xv.w*w;
            }
            float a[4] = {a0, a1, a2, a3};
            #pragma unroll
            for (int ff = 0; ff < 4; ++ff) {
                int s = f0 + ff + 2;
                z[((size_t)b*SEQ + s)*D + d] = a[ff] + pe_val(s, d);
            }
        }
    }
}

// ---------------- split-f16 MFMA GEMM: C = A@W (+bias, epilogues) ----------------
// A: f32 [M][512] row-major, split to hi/lo f16 IN REGISTERS during LDS staging.
// B: hi/lo f16 [N][K]=[512][512] pre-transposed. 3-term hi*hi+hi*lo+lo*hi (~2^-22).
// EPI 0: scatter to (b*H+h, s, dh). EPI 1: +resid, row-major out.
template<int EPI>
__launch_bounds__(256)
__global__ void gemm_f16s(const float* __restrict__ A,
                          const ushort* __restrict__ Bhi, const ushort* __restrict__ Blo,
                          const float* __restrict__ bias, const float* __restrict__ resid,
                          float* __restrict__ out, int M)
{
    __shared__ ushort Ah[128*40], Al[128*40], Bh[128*40], Bl[128*40];
    const int tid = threadIdx.x;
    const int m0 = blockIdx.y * 128, n0 = blockIdx.x * 128;
    const int l = tid & 63, wv = tid >> 6;
    const int wr = wv >> 1, wc = wv & 1;

    f32x4 acc[4][4];
    #pragma unroll
    for (int mi = 0; mi < 4; ++mi)
        #pragma unroll
        for (int ni = 0; ni < 4; ++ni) acc[mi][ni] = (f32x4){0.f, 0.f, 0.f, 0.f};

    // A staging: thread -> row tid>>1, 16 cols at (tid&1)*16
    const int ar_s = tid >> 1, ac_s = (tid & 1) * 16;
    const bool va = (m0 + ar_s) < M;
    // B staging: 2x 8-half chunks per array
    const int r0 = (tid*2) >> 2,   kc0 = ((tid*2) & 3) * 8;
    const int r1 = (tid*2+1) >> 2, kc1 = ((tid*2+1) & 3) * 8;
    const float4 fz = make_float4(0.f, 0.f, 0.f, 0.f);

    for (int kt = 0; kt < 16; ++kt) {
        const int kb = kt * 32;
        float4 a0 = fz, a1 = fz, a2 = fz, a3 = fz;
        if (va) {
            const float4* ap = (const float4*)&A[(size_t)(m0 + ar_s)*D + kb + ac_s];
            a0 = ap[0]; a1 = ap[1]; a2 = ap[2]; a3 = ap[3];
        }
        uint4 bh0 = *(const uint4*)&Bhi[(size_t)(n0+r0)*D + kb + kc0];
        uint4 bh1 = *(const uint4*)&Bhi[(size_t)(n0+r1)*D + kb + kc1];
        uint4 bl0 = *(const uint4*)&Blo[(size_t)(n0+r0)*D + kb + kc0];
        uint4 bl1 = *(const uint4*)&Blo[(size_t)(n0+r1)*D + kb + kc1];

        uint4 AH0, AL0, AH1, AL1;
        split2(a0.x, a0.y, AH0.x, AL0.x); split2(a0.z, a0.w, AH0.y, AL0.y);
        split2(a1.x, a1.y, AH0.z, AL0.z); split2(a1.z, a1.w, AH0.w, AL0.w);
        split2(a2.x, a2.y, AH1.x, AL1.x); split2(a2.z, a2.w, AH1.y, AL1.y);
        split2(a3.x, a3.y, AH1.z, AL1.z); split2(a3.z, a3.w, AH1.w, AL1.w);

        if (kt) __syncthreads();
        *(uint4*)&Ah[ar_s*40 + ac_s]     = AH0;
        *(uint4*)&Ah[ar_s*40 + ac_s + 8] = AH1;
        *(uint4*)&Al[ar_s*40 + ac_s]     = AL0;
        *(uint4*)&Al[ar_s*40 + ac_s + 8] = AL1;
        *(uint4*)&Bh[r0*40 + kc0] = bh0;  *(uint4*)&Bh[r1*40 + kc1] = bh1;
        *(uint4*)&Bl[r0*40 + kc0] = bl0;  *(uint4*)&Bl[r1*40 + kc1] = bl1;
        __syncthreads();

        const int ko = (l >> 4) * 8;
        f16x8 bhf[4], blf[4];
        #pragma unroll
        for (int ni = 0; ni < 4; ++ni) {
            int br = wc*64 + ni*16 + (l & 15);
            bhf[ni] = *(const f16x8*)&Bh[br*40 + ko];
            blf[ni] = *(const f16x8*)&Bl[br*40 + ko];
        }
        #pragma unroll
        for (int mi = 0; mi < 4; ++mi) {
            int ar = wr*64 + mi*16 + (l & 15);
            f16x8 ahf = *(const f16x8*)&Ah[ar*40 + ko];
            f16x8 alf = *(const f16x8*)&Al[ar*40 + ko];
            #pragma unroll
            for (int ni = 0; ni < 4; ++ni) {
                acc[mi][ni] = __builtin_amdgcn_mfma_f32_16x16x32_f16(ahf, bhf[ni], acc[mi][ni], 0, 0, 0);
                acc[mi][ni] = __builtin_amdgcn_mfma_f32_16x16x32_f16(ahf, blf[ni], acc[mi][ni], 0, 0, 0);
                acc[mi][ni] = __builtin_amdgcn_mfma_f32_16x16x32_f16(alf, bhf[ni], acc[mi][ni], 0, 0, 0);
            }
        }
    }

    const int col_base = n0 + wc*64 + (l & 15);
    const int row_base = m0 + wr*64 + ((l >> 4) << 2);
    #pragma unroll
    for (int ni = 0; ni < 4; ++ni) {
        const int col = col_base + ni*16;
        const float bv = bias[col];
        #pragma unroll
        for (int mi = 0; mi < 4; ++mi) {
            #pragma unroll
            for (int e = 0; e < 4; ++e) {
                const int row = row_base + mi*16 + e;
                if (row >= M) continue;
                float val = acc[mi][ni][e] + bv;
                if (EPI == 0) {
                    int bb = row / SEQ;
                    int ss = row - bb*SEQ;
                    int hh = col >> 6, dh = col & 63;
                    out[((size_t)(bb*H + hh)*SEQ + ss)*DH + dh] = val;
                } else {
                    size_t off = (size_t)row*D + col;
                    out[off] = val + resid[off];
                }
            }
        }
    }
}

// ---------------- clustered attention: 1 block (1024 thr) per (b,h) ----------------
// q/k re-read from global each pass (L2-resident; register persistence spills).
// Bitwise-exact kmeans early-exit: unchanged assignments -> centroid fixed point.
__launch_bounds__(1024, 4)
__global__ void attn_kernel(const float* __restrict__ q, const float* __restrict__ kk,
                            const float* __restrict__ v, float* __restrict__ o)
{
    __shared__ float At[NC][SEQP];       // 41.3 KB; doubles as part[16][NC][DH]
    __shared__ float cent[NC][DH];
    __shared__ float tailrow[2][DH];
    __shared__ float cnorm[NC];
    __shared__ int   cnt[NC];
    __shared__ int   chg;
    __shared__ unsigned char assign[1028];
    __shared__ float redA[16][NC];
    __shared__ float redB[16][NC];
    __shared__ float Mc[NC];
    __shared__ float Sinv[NC];

    const int tid = threadIdx.x;
    const int wv = tid >> 6, lane = tid & 63;
    const int bh = blockIdx.x;
    const int b = bh >> 3, h = bh & 7;
    const float* qh = q  + (size_t)bh * SEQ * DH;
    const float* kh = kk + (size_t)bh * SEQ * DH;
    const float* vh = v  + (size_t)bh * SEQ * DH;
    float* oh = o + (size_t)b * SEQ * D + h * DH;
    float* part = &At[0][0];             // [16][NC][DH] flat

    if (tid < NC*DH) ((float*)cent)[tid] = qh[tid];
    if (tid >= NC*DH && tid < NC*DH + 2*DH) ((float*)tailrow)[tid - NC*DH] = qh[1024*DH + (tid - NC*DH)];
    __syncthreads();

    const float4* qrow4 = (const float4*)(qh + (size_t)tid * DH);
    int prev_a = -1, prev_t = -1;

    for (int iter = 0; iter <= KITERS; ++iter) {
        if (tid < NC) {
            float sn = 0.f;
            #pragma unroll
            for (int i = 0; i < 16; ++i) {
                float4 cv = *(const float4*)&cent[tid][i*4];
                sn += cv.x*cv.x + cv.y*cv.y + cv.z*cv.z + cv.w*cv.w;
            }
            cnorm[tid] = sn;
            cnt[tid] = 0;
        }
        if (tid == 0) chg = 0;
        __syncthreads();

        int a_reg;
        {
            float acc[NC];
            #pragma unroll
            for (int c = 0; c < NC; ++c) acc[c] = 0.f;
            #pragma unroll 8
            for (int kq = 0; kq < 16; ++kq) {
                float4 qv = qrow4[kq];
                #pragma unroll
                for (int c = 0; c < NC; ++c) {
                    float4 cv = *(const float4*)&cent[c][kq*4];
                    acc[c] += qv.x*cv.x + qv.y*cv.y + qv.z*cv.z + qv.w*cv.w;
                }
            }
            int best = 0; float bd = 1e30f;
            #pragma unroll
            for (int c = 0; c < NC; ++c) {
                float dd = cnorm[c] - 2.f*acc[c];
                if (dd < bd) { bd = dd; best = c; }
            }
            a_reg = best;
            assign[tid] = (unsigned char)best;
        }
        {
            unsigned long long mm = __ballot(a_reg != prev_a);
            if (lane == 0 && mm) atomicAdd(&chg, 1);
            prev_a = a_reg;
        }
        if (iter < KITERS) {
            #pragma unroll
            for (int c = 0; c < NC; ++c) {
                unsigned long long m = __ballot(a_reg == c);
                if (lane == 0 && m) atomicAdd(&cnt[c], __popcll(m));
            }
        }
        if (tid < 2) {
            int best = 0; float bd = 1e30f;
            #pragma unroll
            for (int c = 0; c < NC; ++c) {
                float acc = 0.f;
                #pragma unroll
                for (int i = 0; i < 64; ++i) acc += tailrow[tid][i]*cent[c][i];
                float dd = cnorm[c] - 2.f*acc;
                if (dd < bd) { bd = dd; best = c; }
            }
            assign[1024 + tid] = (unsigned char)best;
            if (best != prev_t) atomicAdd(&chg, 1);
            prev_t = best;
            if (iter < KITERS) atomicAdd(&cnt[best], 1);
        }
        __syncthreads();
        if (iter == KITERS) break;
        if (chg == 0) break;    // bitwise-exact fixed point

        {
            float accq[NC];
            #pragma unroll
            for (int c = 0; c < NC; ++c) accq[c] = 0.f;
            const int s0 = wv * 64;
            #pragma unroll 8
            for (int i = 0; i < 64; ++i) {
                int s = s0 + i;
                float qv = qh[(size_t)s*DH + lane];
                int c = assign[s];
                #pragma unroll
                for (int cc = 0; cc < NC; ++cc) accq[cc] += (cc == c) ? qv : 0.f;
            }
            if (wv < 2) {
                int c = assign[1024 + wv];
                float qv = tailrow[wv][lane];
                #pragma unroll
                for (int cc = 0; cc < NC; ++cc) accq[cc] += (cc == c) ? qv : 0.f;
            }
            #pragma unroll
            for (int c = 0; c < NC; ++c) part[(wv*NC + c)*DH + lane] = accq[c];
        }
        __syncthreads();
        if (tid < NC*DH) {
            int c = tid >> 6;
            float s = 0.f;
            #pragma unroll
            for (int w = 0; w < 16; ++w) s += part[w*(NC*DH) + tid];
            ((float*)cent)[tid] = s / fmaxf((float)cnt[c], 1.f);
        }
        __syncthreads();
    }

    // ---- logits ----
    if (tid < 2*DH) ((float*)tailrow)[tid] = kh[1024*DH + tid];
    __syncthreads();

    float lg[NC], lgt[NC];
    {
        const float4* krow4 = (const float4*)(kh + (size_t)tid * DH);
        #pragma unroll
        for (int c = 0; c < NC; ++c) lg[c] = 0.f;
        #pragma unroll 8
        for (int kq = 0; kq < 16; ++kq) {
            float4 kv = krow4[kq];
            #pragma unroll
            for (int c = 0; c < NC; ++c) {
                float4 cv = *(const float4*)&cent[c][kq*4];
                lg[c] += kv.x*cv.x + kv.y*cv.y + kv.z*cv.z + kv.w*cv.w;
            }
        }
        #pragma unroll
        for (int c = 0; c < NC; ++c) lg[c] *= 0.125f;
    }
    if (tid < 2) {
        #pragma unroll
        for (int c = 0; c < NC; ++c) {
            float acc = 0.f;
            #pragma unroll
            for (int i = 0; i < 64; ++i) acc += tailrow[tid][i]*cent[c][i];
            lgt[c] = 0.125f * acc;
        }
    }

    #pragma unroll
    for (int c = 0; c < NC; ++c) {
        float m = lg[c];
        if (tid < 2) m = fmaxf(m, lgt[c]);
        #pragma unroll
        for (int off = 32; off; off >>= 1) m = fmaxf(m, __shfl_xor(m, off, 64));
        if (lane == 0) redA[wv][c] = m;
    }
    __syncthreads();
    if (tid < NC) {
        float m = redA[0][tid];
        #pragma unroll
        for (int w = 1; w < 16; ++w) m = fmaxf(m, redA[w][tid]);
        Mc[tid] = m;
    }
    __syncthreads();
    #pragma unroll
    for (int c = 0; c < NC; ++c) lg[c] = expf(lg[c] - Mc[c]);
    if (tid < 2) {
        #pragma unroll
        for (int c = 0; c < NC; ++c) lgt[c] = expf(lgt[c] - Mc[c]);
    }
    #pragma unroll
    for (int c = 0; c < NC; ++c) {
        float s = lg[c] + ((tid < 2) ? lgt[c] : 0.f);
        #pragma unroll
        for (int off = 32; off; off >>= 1) s += __shfl_xor(s, off, 64);
        if (lane == 0) redB[wv][c] = s;
    }
    __syncthreads();
    if (tid < NC) {
        float s = 0.f;
        #pragma unroll
        for (int w = 0; w < 16; ++w) s += redB[w][tid];
        Sinv[tid] = 1.f / s;
    }
    __syncthreads();
    #pragma unroll
    for (int c = 0; c < NC; ++c) At[c][tid] = lg[c] * Sinv[c];
    if (tid < 2) {
        #pragma unroll
        for (int c = 0; c < NC; ++c) At[c][1024 + tid] = lgt[c] * Sinv[c];
    }
    __syncthreads();

    // ---- A @ v ----
    {
        float accv[NC];
        #pragma unroll
        for (int c = 0; c < NC; ++c) accv[c] = 0.f;
        const int s0 = wv * 64;
        for (int i = 0; i < 64; i += 4) {
            float vv0 = vh[(size_t)(s0+i  )*DH + lane];
            float vv1 = vh[(size_t)(s0+i+1)*DH + lane];
            float vv2 = vh[(size_t)(s0+i+2)*DH + lane];
            float vv3 = vh[(size_t)(s0+i+3)*DH + lane];
            #pragma unroll
            for (int c = 0; c < NC; ++c) {
                float4 av = *(const float4*)&At[c][s0+i];
                accv[c] += av.x*vv0 + av.y*vv1 + av.z*vv2 + av.w*vv3;
            }
        }
        if (wv < 2) {
            int s = 1024 + wv;
            float vv = vh[(size_t)s*DH + lane];
            #pragma unroll
            for (int c = 0; c < NC; ++c) accv[c] += At[c][s] * vv;
        }
        __syncthreads();
        #pragma unroll
        for (int c = 0; c < NC; ++c) part[(wv*NC + c)*DH + lane] = accv[c];
    }
    __syncthreads();
    if (tid < NC*DH) {
        float s = 0.f;
        #pragma unroll
        for (int w = 0; w < 16; ++w) s += part[w*(NC*DH) + tid];
        ((float*)cent)[tid] = s;
    }
    __syncthreads();

    {
        const int s0 = wv * 64;
        #pragma unroll 4
        for (int i = 0; i < 64; ++i) {
            int s = s0 + i;
            oh[(size_t)s*D + lane] = cent[assign[s]][lane];
        }
        if (wv < 2) {
            int s = 1024 + wv;
            oh[(size_t)s*D + lane] = cent[assign[s]][lane];
        }
    }
}

// ---------------- fused LN1 + FFN + residual + LN2, one block per row ----------------
__launch_bounds__(256)
__global__ void ffn_ln_kernel(const float* __restrict__ in, float* __restrict__ z,
    const float* __restrict__ g1, const float* __restrict__ c1,
    const float* __restrict__ W1, const float* __restrict__ b1,
    const float* __restrict__ W2, const float* __restrict__ b2,
    const float* __restrict__ g2, const float* __restrict__ c2)
{
    __shared__ float red[8];
    __shared__ float redh[4][DFF];
    const int row = blockIdx.x, tid = threadIdx.x;
    const int lane = tid & 63, wid = tid >> 6;
    const float* r = in + (size_t)row * D;
    float x0 = r[tid], x1 = r[tid + 256];
    float s = x0 + x1, ss = x0*x0 + x1*x1;
    #pragma unroll
    for (int off = 32; off; off >>= 1) {
        s  += __shfl_xor(s,  off, 64);
        ss += __shfl_xor(ss, off, 64);
    }
    if (lane == 0) { red[wid] = s; red[4 + wid] = ss; }
    __syncthreads();
    float tot  = red[0] + red[1] + red[2] + red[3];
    float tot2 = red[4] + red[5] + red[6] + red[7];
    float mean = tot * (1.f/512.f);
    float var  = tot2 * (1.f/512.f) - mean*mean;
    float rstd = rsqrtf(var + 1e-5f);
    float za = (x0 - mean)*rstd*g1[tid]       + c1[tid];
    float zb = (x1 - mean)*rstd*g1[tid + 256] + c1[tid + 256];

    float p[DFF];
    #pragma unroll
    for (int j = 0; j < DFF; ++j)
        p[j] = za * W1[(size_t)tid*DFF + j] + zb * W1[(size_t)(tid+256)*DFF + j];
    #pragma unroll
    for (int off = 32; off; off >>= 1)
        #pragma unroll
        for (int j = 0; j < DFF; ++j) p[j] += __shfl_xor(p[j], off, 64);
    if (lane == 0) {
        #pragma unroll
        for (int j = 0; j < DFF; ++j) redh[wid][j] = p[j];
    }
    __syncthreads();
    float hv[DFF];
    #pragma unroll
    for (int j = 0; j < DFF; ++j)
        hv[j] = fmaxf(redh[0][j] + redh[1][j] + redh[2][j] + redh[3][j] + b1[j], 0.f);
    float y0 = b2[tid], y1 = b2[tid + 256];
    #pragma unroll
    for (int j = 0; j < DFF; ++j) {
        y0 += hv[j] * W2[(size_t)j*D + tid];
        y1 += hv[j] * W2[(size_t)j*D + tid + 256];
    }
    float t0 = za + y0, t1 = zb + y1;
    float s2 = t0 + t1, ss2 = t0*t0 + t1*t1;
    #pragma unroll
    for (int off = 32; off; off >>= 1) {
        s2  += __shfl_xor(s2,  off, 64);
        ss2 += __shfl_xor(ss2, off, 64);
    }
    if (lane == 0) { red[wid] = s2; red[4 + wid] = ss2; }
    __syncthreads();
    float tt  = red[0] + red[1] + red[2] + red[3];
    float tt2 = red[4] + red[5] + red[6] + red[7];
    float m2 = tt * (1.f/512.f);
    float v2 = tt2 * (1.f/512.f) - m2*m2;
    float rstd2 = rsqrtf(v2 + 1e-5f);
    float* zo = z + (size_t)row * D;
    zo[tid]       = (t0 - m2)*rstd2*g2[tid]       + c2[tid];
    zo[tid + 256] = (t1 - m2)*rstd2*g2[tid + 256] + c2[tid + 256];
}

// ---------------- extract mu / logvar ----------------
__launch_bounds__(256)
__global__ void extract_kernel(const float* __restrict__ z, float* __restrict__ out) {
    int i = blockIdx.x * 256 + threadIdx.x;
    if (i >= 2*BATCH*D) return;
    int half = i >> 13;
    int j = i & 8191;
    int b = j >> 9, d = j & 511;
    out[i] = z[((size_t)b*SEQ + half)*D + d];
}

extern "C" void kernel_launch(void* const* d_in, const int* in_sizes, int n_in,
                              void* d_out, int out_size, void* d_ws, size_t ws_size,
                              hipStream_t stream)
{
    const float* x      = (const float*)d_in[0];
    const int*   y      = (const int*)  d_in[1];
    const float* muQ    = (const float*)d_in[3];
    const float* sigQ   = (const float*)d_in[4];
    const float* mu_w   = (const float*)d_in[5];
    const float* mu_b   = (const float*)d_in[6];
    const float* sig_w  = (const float*)d_in[7];
    const float* sig_b  = (const float*)d_in[8];
    const float* skel_w = (const float*)d_in[9];
    const float* skel_b = (const float*)d_in[10];
    const float* Wq     = (const float*)d_in[11];
    const float* bq     = (const float*)d_in[12];
    const float* Wk     = (const float*)d_in[13];
    const float* bk     = (const float*)d_in[14];
    const float* Wv     = (const float*)d_in[15];
    const float* bv     = (const float*)d_in[16];
    const float* Wo     = (const float*)d_in[17];
    const float* bo     = (const float*)d_in[18];
    const float* g1     = (const float*)d_in[19];
    const float* c1     = (const float*)d_in[20];
    const float* g2     = (const float*)d_in[21];
    const float* c2     = (const float*)d_in[22];
    const float* W1     = (const float*)d_in[23];
    const float* b1     = (const float*)d_in[24];
    const float* W2     = (const float*)d_in[25];
    const float* b2     = (const float*)d_in[26];

    // workspace: 5 f32 bufs (168.1 MB) + per-layer split weights (4.2 MB) = 172.3 MB
    float*  z    = (float*)d_ws;
    float*  ob   = z  + NBUF;
    float*  qb   = ob + NBUF;
    float*  kb   = qb + NBUF;
    float*  vb   = kb + NBUF;
    ushort* wThi = (ushort*)(vb + NBUF);   // [4][512][512] f16 hi
    ushort* wTlo = wThi + 4*DD;            // [4][512][512] f16 lo

    embed_kernel<<<dim3(258, BATCH), 256, 0, stream>>>(
        x, y, muQ, sigQ, mu_w, mu_b, sig_w, sig_b, skel_w, skel_b, z);

    dim3 ggrid(4, 129);
    for (int l = 0; l < NLAYERS; ++l) {
        convert_w<<<dim3(8, 8, 4), 256, 0, stream>>>(
            Wq + l*DD, Wk + l*DD, Wv + l*DD, Wo + l*DD, wThi, wTlo);
        gemm_f16s<0><<<ggrid, 256, 0, stream>>>(z,  wThi,        wTlo,        bq + l*D, nullptr, qb, MR);
        gemm_f16s<0><<<ggrid, 256, 0, stream>>>(z,  wThi + DD,   wTlo + DD,   bk + l*D, nullptr, kb, MR);
        gemm_f16s<0><<<ggrid, 256, 0, stream>>>(z,  wThi + 2*DD, wTlo + 2*DD, bv + l*D, nullptr, vb, MR);
        attn_kernel<<<BATCH*H, 1024, 0, stream>>>(qb, kb, vb, ob);
        gemm_f16s<1><<<ggrid, 256, 0, stream>>>(ob, wThi + 3*DD, wTlo + 3*DD, bo + l*D, z, qb, MR);
        ffn_ln_kernel<<<MR, 256, 0, stream>>>(qb, z,
            g1 + (size_t)l*D, c1 + (size_t)l*D,
            W1 + (size_t)l*D*DFF, b1 + (size_t)l*DFF,
            W2 + (size_t)l*DFF*D, b2 + (size_t)l*D,
            g2 + (size_t)l*D, c2 + (size_t)l*D);
    }
    extract_kernel<<<64, 256, 0, stream>>>(z, (float*)d_out);

    (void)in_sizes; (void)n_in; (void)out_size; (void)ws_size;
}